// Round 10
// baseline (380.884 us; speedup 1.0000x reference)
//
#include <hip/hip_runtime.h>
#include <math.h>

// Problem constants (B=8, Cin=Cout=64, H=W=64, 3x3 kernel pad 1)
#define NB     8
#define NC     64
#define HW     4096           // 64*64
#define PLANE  2097152        // NB*NC*HW

// Workspace layout (float-slot offsets)
#define WS_WB     0           // bf16 wB[8][72][64][8]   (294912 bf16 = 147456 f)
#define WS_OWB    147456      // bf16 owB[8][72][32][8]  (147456 bf16 = 73728 f)
#define WS_OB     221184      // f32 obAll[8][27]
#define WS_GATES  221400      // f32 gates_scr[4][8][64][4096] = 8388608 (D-scrambled)
#define WS_XT     8610008     // bf16 xT[8][4096][64] HWC  (1048576 f)
#define WS_HT     9658584     // bf16 hT[8][4096][64] HWC  (1048576 f)
// total = 10707160 floats = 42.8 MB

typedef __bf16 bf16x8 __attribute__((ext_vector_type(8)));
typedef float  f32x4  __attribute__((ext_vector_type(4)));
typedef _Float16 f16x4 __attribute__((ext_vector_type(4)));

struct Params {
    const float* x; const float* h; const float* c;
    const float* w[8]; const float* ow[8]; const float* ob[8];
    const float* bi; const float* bf; const float* bc; const float* bo;
    const float* wci; const float* wcf; const float* wco;
    float* out; float* ws;
};

__device__ __forceinline__ float sigf(float v) { return 1.f / (1.f + __expf(-v)); }
__device__ __forceinline__ float tanhfast(float v) {
    return 1.f - 2.f / (__expf(2.f * v) + 1.f);
}
__device__ __forceinline__ unsigned short f2bf(float v) {
    __bf16 b = (__bf16)v;
    return __builtin_bit_cast(unsigned short, b);
}
// bf16 pair unpack: lo/hi halves of a dword -> f32 (1 inst each)
__device__ __forceinline__ float blo(unsigned d) { return __builtin_bit_cast(float, d << 16); }
__device__ __forceinline__ float bhi(unsigned d) { return __builtin_bit_cast(float, d & 0xffff0000u); }

// ---------------------------------------------------------------------------
// K0 (merged): weight B-frag packing + biases (blocks 0..1728), and
//   CHW fp32 -> HWC bf16 transpose of x/h (blocks 1729..2752).
// ---------------------------------------------------------------------------
__global__ __launch_bounds__(256) void k0_prep(Params p) {
    if (blockIdx.x < 1729) {
        int i = blockIdx.x * 256 + threadIdx.x;
        unsigned short* wb  = (unsigned short*)(p.ws + WS_WB);
        unsigned short* owb = (unsigned short*)(p.ws + WS_OWB);
        if (i < 294912) {
            int br = i / 36864; int r = i % 36864;
            int kgrp = r >> 9; int o = (r >> 3) & 63; int j = r & 7;
            int k = kgrp * 8 + j;
            int ktap = k >> 6; int c = k & 63;
            wb[i] = f2bf(p.w[br][(o * 64 + c) * 9 + ktap]);
        } else if (i < 294912 + 147456) {
            int ii = i - 294912;
            int br = ii / 18432; int r = ii % 18432;
            int kgrp = r >> 8; int o = (r >> 3) & 31; int j = r & 7;
            int k = kgrp * 8 + j;
            int ktap = k >> 6; int c = k & 63;
            float v = (o < 27) ? p.ow[br][(o * 64 + c) * 9 + ktap] : 0.f;
            owb[ii] = f2bf(v);
        } else if (i < 294912 + 147456 + 216) {
            int ii = i - 442368;
            int br = ii / 27; int j = ii % 27;
            p.ws[WS_OB + ii] = p.ob[br][j];
        }
        return;
    }
    __shared__ float tile[64][65];
    int bid = blockIdx.x - 1729;
    int row = bid & 63; int b = (bid >> 6) & 7; int ten = bid >> 9;
    const float* src = ten ? p.h : p.x;
    unsigned short* dst = (unsigned short*)(p.ws + (ten ? WS_HT : WS_XT));
    int t = threadIdx.x; int lane = t & 63; int w4 = t >> 6;
#pragma unroll
    for (int i = 0; i < 16; ++i) {
        int c = i * 4 + w4;
        tile[c][lane] = src[((size_t)(b * 64 + c) << 12) + row * 64 + lane];
    }
    __syncthreads();
#pragma unroll
    for (int i = 0; i < 16; ++i) {
        int px = i * 4 + w4;
        dst[((size_t)(b * 4096 + row * 64 + px) << 6) + lane] = f2bf(tile[lane][px]);
    }
}

// ---------------------------------------------------------------------------
// K2 v17 (R5 full-window structure @ 3 blocks/CU): offset-conv+deform+MFMA.
//   (Resubmission — R9 was a GPU-acquisition timeout; kernel never ran.)
//   R8 post-mortem: 36KB arena did NOT buy a 4th block — unified reg file
//   caps at 3 waves/SIMD (76 arch + ~64 acc = 140 > 128; R7 calibrated
//   acc~64 when forced-64-arch spilled). 4-block lever is a dead end.
//   At fixed 3 blocks, minimize work: R5's full-window pipeline (1 stage
//   pass/sub, 4 barriers/sub, single 9-tap both-halves gather) did 134us
//   at TWO blocks — strictly less work than v16's half-split. Shrink ITS
//   arena to fit 3 blocks without touching the pipeline:
//     - sWp f16x4 (4608B, proven R7/R8)
//     - sOff ALIASED over sA/sWp (phase A split: read sOff->regs, barrier,
//       compute+write sA/sWp; static 3-item unroll). Saves 7128B, +1 barrier.
//     - arena = 40960 win + 4608 sA + 4608 sWp = 50176B -> 3 blocks/CU.
//   __launch_bounds__(256,3): budget 170 >= est ~156 total -> no crush.
//   Carried: LDS window gather + XOR swizzle (R4), B-frag reg pipeline (R5),
//   far-bit global fallback, XCD swizzle b=bid&7, D-scrambled epilogue.
// ---------------------------------------------------------------------------
__global__ __launch_bounds__(256, 3) void k2_fused(Params p) {
    __shared__ __align__(16) unsigned char arena[50176];
    // win:  [0, 40960)      bf16 [5][64px][64ch], byte=((r*64+px)<<7)+seg*16 ^ ((px&7)<<4)
    // sA:   [40960, 45568)  uint2 [9][64]  packed clamped pix (+far bit31 in .x)
    // sWp:  [45568, 50176)  f16x4 [9][64]  folded bilinear weights
    // sOff: [40960, 48088)  f32 [27][66]   ALIASED over sA/sWp (phased)
    uint2* sA   = (uint2*)(arena + 40960);
    f16x4* sWp  = (f16x4*)(arena + 45568);
    float* sOff = (float*)(arena + 40960);

    int bid = blockIdx.x;
    // XCD-aware decode: same-b blocks share an XCD's L2.
    int b = bid & 7; int gate = (bid >> 3) & 3; int row = bid >> 5;
    int t = threadIdx.x; int l = t & 63; int w = t >> 6;
    int q = l >> 4; int n = l & 15;
    int pxl = w * 16 + n;

    const unsigned short* wBp = (const unsigned short*)(p.ws + WS_WB);
    const unsigned short* owb = (const unsigned short*)(p.ws + WS_OWB);

    // per-lane gather address bias: byte = (pix<<7) + qb, then ^ ((pix&7)<<4)
    int qb = q * 16 - (row - 2) * 8192;

    f32x4 acc[4];
#pragma unroll
    for (int ot = 0; ot < 4; ++ot) acc[ot] = (f32x4){0.f, 0.f, 0.f, 0.f};

    for (int sub = 0; sub < 2; ++sub) {
        int br = gate * 2 + sub;
        const unsigned short* inT =
            (const unsigned short*)(p.ws + (sub ? WS_HT : WS_XT)) + ((size_t)b << 18);
        const float* obp = p.ws + WS_OB + br * 27;

        // ---- stage full 5-row window (rows row-2..row+2, zero-filled OOB) ----
        __syncthreads();           // win/sA/sWp free (prev sub's gather done)
#pragma unroll
        for (int it = 0; it < 10; ++it) {
            int u = t + it * 256;                  // u in [0,2560)
            int r = u >> 9; int px = (u >> 3) & 63; int seg = u & 7;
            int grow = row - 2 + r;
            uint4 v = {0u, 0u, 0u, 0u};
            if ((unsigned)grow < 64u)
                v = *(const uint4*)(inT + (((size_t)grow * 64 + px) << 6) + seg * 8);
            unsigned byte = ((unsigned)u << 4) ^ (((unsigned)px & 7u) << 4);
            *(uint4*)(arena + byte) = v;
        }
        __syncthreads();

        // ---- fused offset conv (pipelined): M=16 px, N=32, K=576 ----
        auto loadA_oc = [&](int u) -> bf16x8 {
            int dy = u / 6; int s = u - dy * 6;
            int spx = pxl + (s >> 1) - 1;              // [-1, 64]
            int spc = min(max(spx, 0), 63);
            int cgb = (s & 1) * 4 + q;
            unsigned byte = ((unsigned)(((dy + 1) * 64 + spc) << 7) + cgb * 16)
                            ^ (((unsigned)spc & 7u) << 4);
            bf16x8 af = *(const bf16x8*)(arena + byte);
            if ((unsigned)spx >= 64u) {                // zero halo columns
#pragma unroll
                for (int z = 0; z < 8; ++z) af[z] = (__bf16)0.f;
            }
            return af;
        };
        auto loadB_oc = [&](int u, int ot) -> bf16x8 {
            int dy = u / 6; int s = u - dy * 6;
            int kb = (br * 72 + dy * 24 + s * 4 + q) * 32;
            return *(const bf16x8*)(owb + (size_t)(kb + ot * 16 + n) * 8);
        };
        f32x4 c0 = (f32x4){0.f,0.f,0.f,0.f}, c1 = (f32x4){0.f,0.f,0.f,0.f};
        f32x4 c2 = (f32x4){0.f,0.f,0.f,0.f}, c3 = (f32x4){0.f,0.f,0.f,0.f};
        bf16x8 eA = loadA_oc(0), eB0 = loadB_oc(0, 0), eB1 = loadB_oc(0, 1);
        bf16x8 dA = loadA_oc(1), dB0 = loadB_oc(1, 0), dB1 = loadB_oc(1, 1);
#pragma unroll 1
        for (int u2 = 0; u2 < 9; ++u2) {
            bf16x8 neA = eA, neB0 = eB0, neB1 = eB1;
            bf16x8 ndA = dA, ndB0 = dB0, ndB1 = dB1;
            if (u2 < 8) {
                neA = loadA_oc(2 * u2 + 2); neB0 = loadB_oc(2 * u2 + 2, 0); neB1 = loadB_oc(2 * u2 + 2, 1);
                ndA = loadA_oc(2 * u2 + 3); ndB0 = loadB_oc(2 * u2 + 3, 0); ndB1 = loadB_oc(2 * u2 + 3, 1);
            }
            c0 = __builtin_amdgcn_mfma_f32_16x16x32_bf16(eA, eB0, c0, 0, 0, 0);
            c1 = __builtin_amdgcn_mfma_f32_16x16x32_bf16(eA, eB1, c1, 0, 0, 0);
            c2 = __builtin_amdgcn_mfma_f32_16x16x32_bf16(dA, dB0, c2, 0, 0, 0);
            c3 = __builtin_amdgcn_mfma_f32_16x16x32_bf16(dA, dB1, c3, 0, 0, 0);
            eA = neA; eB0 = neB0; eB1 = neB1;
            dA = ndA; dB0 = ndB0; dB1 = ndB1;
        }
        f32x4 acc2[2];
        acc2[0] = c0 + c2;
        acc2[1] = c1 + c3;

        // D-frags (+bias) -> sOff[j][px] (ALIASED region; prev gather done
        // since the pre-stage barrier); j=ot*16+n, px=w*16+q*4+r; j<27 only
#pragma unroll
        for (int ot = 0; ot < 2; ++ot) {
            int j = ot * 16 + n;
            if (j < 27) {
                float bias = obp[j];
#pragma unroll
                for (int r = 0; r < 4; ++r)
                    sOff[j * 66 + w * 16 + q * 4 + r] = acc2[ot][r] + bias;
            }
        }
        __syncthreads();   // sOff visible

        // ---- Phase A (split for aliasing): read sOff -> regs, barrier,
        //      compute + write sA/sWp (overwrites sOff region) ----
        int iA = t, iB = t + 256, iC = t + 512;        // iB < 576 always
        float ady, adx, amm, bdy, bdx, bmm;
        float cdy = 0.f, cdx = 0.f, cmm = 0.f;
        {
            int px = iA & 63, k = iA >> 6;
            ady = sOff[(2 * k) * 66 + px]; adx = sOff[(2 * k + 1) * 66 + px];
            amm = sOff[(18 + k) * 66 + px];
            px = iB & 63; k = iB >> 6;
            bdy = sOff[(2 * k) * 66 + px]; bdx = sOff[(2 * k + 1) * 66 + px];
            bmm = sOff[(18 + k) * 66 + px];
            if (iC < 576) {
                px = iC & 63; k = iC >> 6;
                cdy = sOff[(2 * k) * 66 + px]; cdx = sOff[(2 * k + 1) * 66 + px];
                cmm = sOff[(18 + k) * 66 + px];
            }
        }
        __syncthreads();   // all sOff reads done; sA/sWp region writable

        auto phaseA_item = [&](int i2, float dy, float dx, float mm) {
            int px = i2 & 63; int k = i2 >> 6;
            float m = sigf(mm);
            int ki = k / 3, kj = k % 3;
            float py  = (float)(row + ki - 1) + dy;
            float pxx = (float)(px + kj - 1) + dx;
            float y0f = floorf(py), x0f = floorf(pxx);
            float wy = py - y0f, wx = pxx - x0f;
            int y0 = (int)y0f, x0 = (int)x0f;
            float y0i = ((unsigned)y0 < 64u) ? 1.f : 0.f;
            float y1i = ((unsigned)(y0 + 1) < 64u) ? 1.f : 0.f;
            float x0i = ((unsigned)x0 < 64u) ? 1.f : 0.f;
            float x1i = ((unsigned)(x0 + 1) < 64u) ? 1.f : 0.f;
            float w00 = (1.f - wy) * (1.f - wx) * m * y0i * x0i;
            float w01 = (1.f - wy) * wx         * m * y0i * x1i;
            float w10 = wy         * (1.f - wx) * m * y1i * x0i;
            float w11 = wy         * wx         * m * y1i * x1i;
            int cy0 = min(max(y0, 0), 63),     cy1 = min(max(y0 + 1, 0), 63);
            int cx0 = min(max(x0, 0), 63),     cx1 = min(max(x0 + 1, 0), 63);
            // far: clamped corner row outside staged window [row-2, row+2]
            int s0 = cy0 - (row - 2); int s1 = cy1 - (row - 2);
            unsigned farb = (((unsigned)s0 > 4u) || ((unsigned)s1 > 4u)) ? 0x80000000u : 0u;
            sA[k * 64 + px] = make_uint2(((unsigned)(cy0 * 64 + cx0) | ((unsigned)(cy0 * 64 + cx1) << 16)) | farb,
                                         (unsigned)(cy1 * 64 + cx0) | ((unsigned)(cy1 * 64 + cx1) << 16));
            sWp[k * 64 + px] = (f16x4){(_Float16)w00, (_Float16)w01, (_Float16)w10, (_Float16)w11};
        };
        phaseA_item(iA, ady, adx, amm);
        phaseA_item(iB, bdy, bdx, bmm);
        if (iC < 576) phaseA_item(iC, cdy, cdx, cmm);
        __syncthreads();

        // ---- pipelined LDS gather (both halves) + B-frag register pipeline ----
        const unsigned short* cbase = inT + q * 8;
        auto loadB_mn = [&](int S, int ot) -> bf16x8 {
            int kb = (br * 72 + S * 4 + q) * 64;
            return *(const bf16x8*)(wBp + (size_t)(kb + ot * 16 + n) * 8);
        };

#define PROC(Ca, Cb, Cc, Cd, WV, Wa, Wb, Wc, Wd)                               \
        {                                                                      \
            float sacc[8];                                                     \
            sacc[0] = WV.x * blo(Ca.x); sacc[1] = WV.x * bhi(Ca.x);            \
            sacc[2] = WV.x * blo(Ca.y); sacc[3] = WV.x * bhi(Ca.y);            \
            sacc[4] = WV.x * blo(Ca.z); sacc[5] = WV.x * bhi(Ca.z);            \
            sacc[6] = WV.x * blo(Ca.w); sacc[7] = WV.x * bhi(Ca.w);            \
            sacc[0] += WV.y * blo(Cb.x); sacc[1] += WV.y * bhi(Cb.x);          \
            sacc[2] += WV.y * blo(Cb.y); sacc[3] += WV.y * bhi(Cb.y);          \
            sacc[4] += WV.y * blo(Cb.z); sacc[5] += WV.y * bhi(Cb.z);          \
            sacc[6] += WV.y * blo(Cb.w); sacc[7] += WV.y * bhi(Cb.w);          \
            sacc[0] += WV.z * blo(Cc.x); sacc[1] += WV.z * bhi(Cc.x);          \
            sacc[2] += WV.z * blo(Cc.y); sacc[3] += WV.z * bhi(Cc.y);          \
            sacc[4] += WV.z * blo(Cc.z); sacc[5] += WV.z * bhi(Cc.z);          \
            sacc[6] += WV.z * blo(Cc.w); sacc[7] += WV.z * bhi(Cc.w);          \
            sacc[0] += WV.w * blo(Cd.x); sacc[1] += WV.w * bhi(Cd.x);          \
            sacc[2] += WV.w * blo(Cd.y); sacc[3] += WV.w * bhi(Cd.y);          \
            sacc[4] += WV.w * blo(Cd.z); sacc[5] += WV.w * bhi(Cd.z);          \
            sacc[6] += WV.w * blo(Cd.w); sacc[7] += WV.w * bhi(Cd.w);          \
            bf16x8 af;                                                         \
            _Pragma("unroll")                                                  \
            for (int j = 0; j < 8; ++j) af[j] = (__bf16)sacc[j];               \
            acc[0] = __builtin_amdgcn_mfma_f32_16x16x32_bf16(af, Wa, acc[0], 0, 0, 0); \
            acc[1] = __builtin_amdgcn_mfma_f32_16x16x32_bf16(af, Wb, acc[1], 0, 0, 0); \
            acc[2] = __builtin_amdgcn_mfma_f32_16x16x32_bf16(af, Wc, acc[2], 0, 0, 0); \
            acc[3] = __builtin_amdgcn_mfma_f32_16x16x32_bf16(af, Wd, acc[3], 0, 0, 0); \
        }

        // prologue: tap 0 addresses, corner LDS loads (both halves), B-frags
        uint2 aa = sA[pxl];
        f16x4 wv4 = sWp[pxl];
        float4 wv = make_float4((float)wv4[0], (float)wv4[1], (float)wv4[2], (float)wv4[3]);
        unsigned p00 = aa.x & 0xFFFu, p01 = (aa.x >> 16) & 0xFFFu;
        unsigned p10 = aa.y & 0xFFFu, p11 = aa.y >> 16;
        unsigned a00 = (unsigned)(((int)(p00 << 7)) + qb) ^ ((p00 & 7u) << 4);
        unsigned a01 = (unsigned)(((int)(p01 << 7)) + qb) ^ ((p01 & 7u) << 4);
        unsigned a10 = (unsigned)(((int)(p10 << 7)) + qb) ^ ((p10 & 7u) << 4);
        unsigned a11 = (unsigned)(((int)(p11 << 7)) + qb) ^ ((p11 & 7u) << 4);
        uint4 C0a = *(const uint4*)(arena + a00);
        uint4 C0b = *(const uint4*)(arena + a01);
        uint4 C0c = *(const uint4*)(arena + a10);
        uint4 C0d = *(const uint4*)(arena + a11);
        uint4 C1a = *(const uint4*)(arena + (a00 ^ 64u));
        uint4 C1b = *(const uint4*)(arena + (a01 ^ 64u));
        uint4 C1c = *(const uint4*)(arena + (a10 ^ 64u));
        uint4 C1d = *(const uint4*)(arena + (a11 ^ 64u));
        if (aa.x & 0x80000000u) {     // rare: window miss -> exact global path
            C0a = *(const uint4*)(cbase + (p00 << 6));
            C0b = *(const uint4*)(cbase + (p01 << 6));
            C0c = *(const uint4*)(cbase + (p10 << 6));
            C0d = *(const uint4*)(cbase + (p11 << 6));
            C1a = *(const uint4*)(cbase + (p00 << 6) + 32);
            C1b = *(const uint4*)(cbase + (p01 << 6) + 32);
            C1c = *(const uint4*)(cbase + (p10 << 6) + 32);
            C1d = *(const uint4*)(cbase + (p11 << 6) + 32);
        }
        bf16x8 B0a = loadB_mn(0, 0), B0b = loadB_mn(0, 1), B0c = loadB_mn(0, 2), B0d = loadB_mn(0, 3);
        bf16x8 B1a = loadB_mn(1, 0), B1b = loadB_mn(1, 1), B1c = loadB_mn(1, 2), B1d = loadB_mn(1, 3);
#pragma unroll 1
        for (int ktap = 0; ktap < 9; ++ktap) {
            uint4 N0a = C0a, N0b = C0b, N0c = C0c, N0d = C0d;
            uint4 N1a = C1a, N1b = C1b, N1c = C1c, N1d = C1d;
            float4 wvn = wv;
            bf16x8 nB0a = B0a, nB0b = B0b, nB0c = B0c, nB0d = B0d;
            bf16x8 nB1a = B1a, nB1b = B1b, nB1c = B1c, nB1d = B1d;
            if (ktap < 8) {      // prefetch next tap: A corners (LDS) + B (global)
                uint2 aan = sA[(ktap + 1) * 64 + pxl];
                f16x4 wvn4 = sWp[(ktap + 1) * 64 + pxl];
                wvn = make_float4((float)wvn4[0], (float)wvn4[1], (float)wvn4[2], (float)wvn4[3]);
                unsigned q00 = aan.x & 0xFFFu, q01 = (aan.x >> 16) & 0xFFFu;
                unsigned q10 = aan.y & 0xFFFu, q11 = aan.y >> 16;
                unsigned b00 = (unsigned)(((int)(q00 << 7)) + qb) ^ ((q00 & 7u) << 4);
                unsigned b01 = (unsigned)(((int)(q01 << 7)) + qb) ^ ((q01 & 7u) << 4);
                unsigned b10 = (unsigned)(((int)(q10 << 7)) + qb) ^ ((q10 & 7u) << 4);
                unsigned b11 = (unsigned)(((int)(q11 << 7)) + qb) ^ ((q11 & 7u) << 4);
                N0a = *(const uint4*)(arena + b00);
                N0b = *(const uint4*)(arena + b01);
                N0c = *(const uint4*)(arena + b10);
                N0d = *(const uint4*)(arena + b11);
                N1a = *(const uint4*)(arena + (b00 ^ 64u));
                N1b = *(const uint4*)(arena + (b01 ^ 64u));
                N1c = *(const uint4*)(arena + (b10 ^ 64u));
                N1d = *(const uint4*)(arena + (b11 ^ 64u));
                if (aan.x & 0x80000000u) {
                    N0a = *(const uint4*)(cbase + (q00 << 6));
                    N0b = *(const uint4*)(cbase + (q01 << 6));
                    N0c = *(const uint4*)(cbase + (q10 << 6));
                    N0d = *(const uint4*)(cbase + (q11 << 6));
                    N1a = *(const uint4*)(cbase + (q00 << 6) + 32);
                    N1b = *(const uint4*)(cbase + (q01 << 6) + 32);
                    N1c = *(const uint4*)(cbase + (q10 << 6) + 32);
                    N1d = *(const uint4*)(cbase + (q11 << 6) + 32);
                }
                nB0a = loadB_mn(2 * ktap + 2, 0); nB0b = loadB_mn(2 * ktap + 2, 1);
                nB0c = loadB_mn(2 * ktap + 2, 2); nB0d = loadB_mn(2 * ktap + 2, 3);
                nB1a = loadB_mn(2 * ktap + 3, 0); nB1b = loadB_mn(2 * ktap + 3, 1);
                nB1c = loadB_mn(2 * ktap + 3, 2); nB1d = loadB_mn(2 * ktap + 3, 3);
            }
            // process current tap (half-0 then half-1) with preloaded B
            PROC(C0a, C0b, C0c, C0d, wv, B0a, B0b, B0c, B0d)
            PROC(C1a, C1b, C1c, C1d, wv, B1a, B1b, B1c, B1d)
            C0a = N0a; C0b = N0b; C0c = N0c; C0d = N0d;
            C1a = N1a; C1b = N1b; C1c = N1c; C1d = N1d;
            B0a = nB0a; B0b = nB0b; B0c = nB0c; B0d = nB0d;
            B1a = nB1a; B1b = nB1b; B1c = nB1c; B1d = nB1d;
            wv = wvn;
        }
#undef PROC
    }

    // epilogue: direct D-scrambled coalesced store; K3 decodes.
    float* gp = p.ws + WS_GATES + ((size_t)((gate * 8 + b) * 64 + row) << 12);
#pragma unroll
    for (int ot = 0; ot < 4; ++ot)
        *(float4*)(gp + ((w * 4 + ot) * 64 + l) * 4) = *(float4*)&acc[ot];
}

// ---------------------------------------------------------------------------
// K3: pointwise ConvLSTM combine, reading D-scrambled gates (coalesced) and
//   decoding (o,px) for c/out access (16B-segment granularity).
//   grid: 8192 blocks of 256.
// ---------------------------------------------------------------------------
__global__ __launch_bounds__(256) void k3_lstm(Params p) {
    int T = blockIdx.x * 256 + threadIdx.x;        // [b][row][i] over scrambled
    int i = T & 4095; int row = (T >> 12) & 63; int b = T >> 18;
    const float* gp = p.ws + WS_GATES;
    size_t base = ((size_t)(b * 64 + row) << 12) + i;
    float gi = gp[base];
    float gf = gp[base + 1 * PLANE];
    float gc = gp[base + 2 * PLANE];
    float go = gp[base + 3 * PLANE];
    // decode scramble: i = ((w*4+ot)*64 + l)*4 + r
    int r = i & 3; int l = (i >> 2) & 63; int u = i >> 8;
    int w = u >> 2; int ot = u & 3;
    int o = ot * 16 + (l & 15);
    int px = w * 16 + (l >> 4) * 4 + r;
    size_t cidx = ((size_t)(b * 64 + o) << 12) + row * 64 + px;
    float cold = p.c[cidx];
    float ig = sigf(gi + cold * p.wci[o] + p.bi[o]);
    float fg = sigf(gf + cold * p.wcf[o] + p.bf[o]);
    float cn = fg * cold + ig * tanhfast(gc + p.bc[o]);
    float og = sigf(go + cn * p.wco[o] + p.bo[o]);
    p.out[cidx] = og * tanhfast(cn);
    p.out[cidx + PLANE] = cn;
}

// ---------------------------------------------------------------------------
extern "C" void kernel_launch(void* const* d_in, const int* in_sizes, int n_in,
                              void* d_out, int out_size, void* d_ws, size_t ws_size,
                              hipStream_t stream) {
    (void)in_sizes; (void)n_in; (void)out_size; (void)ws_size;
    Params P;
    P.x = (const float*)d_in[0];
    P.h = (const float*)d_in[1];
    P.c = (const float*)d_in[2];
    for (int i = 0; i < 8; ++i) {
        P.w[i]  = (const float*)d_in[3 + 3 * i];
        P.ow[i] = (const float*)d_in[4 + 3 * i];
        P.ob[i] = (const float*)d_in[5 + 3 * i];
    }
    P.bi  = (const float*)d_in[27];
    P.bf  = (const float*)d_in[28];
    P.bc  = (const float*)d_in[29];
    P.bo  = (const float*)d_in[30];
    P.wci = (const float*)d_in[31];
    P.wcf = (const float*)d_in[32];
    P.wco = (const float*)d_in[33];
    P.out = (float*)d_out;
    P.ws  = (float*)d_ws;

    k0_prep   <<<dim3(2753), dim3(256), 0, stream>>>(P);
    k2_fused  <<<dim3(2048), dim3(256), 0, stream>>>(P);
    k3_lstm   <<<dim3(8192), dim3(256), 0, stream>>>(P);
}

// Round 11
// 274.683 us; speedup vs baseline: 1.3866x; 1.3866x over previous
//
#include <hip/hip_runtime.h>
#include <math.h>

// Problem constants (B=8, Cin=Cout=64, H=W=64, 3x3 kernel pad 1)
#define NB     8
#define NC     64
#define HW     4096           // 64*64
#define PLANE  2097152        // NB*NC*HW

// Workspace layout (float-slot offsets)
#define WS_WB     0           // bf16 wB[8][72][64][8]   (294912 bf16 = 147456 f)
#define WS_OWB    147456      // bf16 owB[8][72][32][8]  (147456 bf16 = 73728 f)
#define WS_OB     221184      // f32 obAll[8][27]
#define WS_GATES  221400      // f32 gates_scr[4][8][64][4096] = 8388608 (D-scrambled)
#define WS_XT     8610008     // bf16 xT[8][4096][64] HWC  (1048576 f)
#define WS_HT     9658584     // bf16 hT[8][4096][64] HWC  (1048576 f)
// total = 10707160 floats = 42.8 MB

typedef __bf16 bf16x8 __attribute__((ext_vector_type(8)));
typedef float  f32x4  __attribute__((ext_vector_type(4)));
typedef _Float16 f16x4 __attribute__((ext_vector_type(4)));

struct Params {
    const float* x; const float* h; const float* c;
    const float* w[8]; const float* ow[8]; const float* ob[8];
    const float* bi; const float* bf; const float* bc; const float* bo;
    const float* wci; const float* wcf; const float* wco;
    float* out; float* ws;
};

__device__ __forceinline__ float sigf(float v) { return 1.f / (1.f + __expf(-v)); }
__device__ __forceinline__ float tanhfast(float v) {
    return 1.f - 2.f / (__expf(2.f * v) + 1.f);
}
__device__ __forceinline__ unsigned short f2bf(float v) {
    __bf16 b = (__bf16)v;
    return __builtin_bit_cast(unsigned short, b);
}
// bf16 pair unpack: lo/hi halves of a dword -> f32 (1 inst each)
__device__ __forceinline__ float blo(unsigned d) { return __builtin_bit_cast(float, d << 16); }
__device__ __forceinline__ float bhi(unsigned d) { return __builtin_bit_cast(float, d & 0xffff0000u); }

// ---------------------------------------------------------------------------
// K0 (merged): weight B-frag packing + biases (blocks 0..1728), and
//   CHW fp32 -> HWC bf16 transpose of x/h (blocks 1729..2752).
// ---------------------------------------------------------------------------
__global__ __launch_bounds__(256) void k0_prep(Params p) {
    if (blockIdx.x < 1729) {
        int i = blockIdx.x * 256 + threadIdx.x;
        unsigned short* wb  = (unsigned short*)(p.ws + WS_WB);
        unsigned short* owb = (unsigned short*)(p.ws + WS_OWB);
        if (i < 294912) {
            int br = i / 36864; int r = i % 36864;
            int kgrp = r >> 9; int o = (r >> 3) & 63; int j = r & 7;
            int k = kgrp * 8 + j;
            int ktap = k >> 6; int c = k & 63;
            wb[i] = f2bf(p.w[br][(o * 64 + c) * 9 + ktap]);
        } else if (i < 294912 + 147456) {
            int ii = i - 294912;
            int br = ii / 18432; int r = ii % 18432;
            int kgrp = r >> 8; int o = (r >> 3) & 31; int j = r & 7;
            int k = kgrp * 8 + j;
            int ktap = k >> 6; int c = k & 63;
            float v = (o < 27) ? p.ow[br][(o * 64 + c) * 9 + ktap] : 0.f;
            owb[ii] = f2bf(v);
        } else if (i < 294912 + 147456 + 216) {
            int ii = i - 442368;
            int br = ii / 27; int j = ii % 27;
            p.ws[WS_OB + ii] = p.ob[br][j];
        }
        return;
    }
    __shared__ float tile[64][65];
    int bid = blockIdx.x - 1729;
    int row = bid & 63; int b = (bid >> 6) & 7; int ten = bid >> 9;
    const float* src = ten ? p.h : p.x;
    unsigned short* dst = (unsigned short*)(p.ws + (ten ? WS_HT : WS_XT));
    int t = threadIdx.x; int lane = t & 63; int w4 = t >> 6;
#pragma unroll
    for (int i = 0; i < 16; ++i) {
        int c = i * 4 + w4;
        tile[c][lane] = src[((size_t)(b * 64 + c) << 12) + row * 64 + lane];
    }
    __syncthreads();
#pragma unroll
    for (int i = 0; i < 16; ++i) {
        int px = i * 4 + w4;
        dst[((size_t)(b * 4096 + row * 64 + px) << 6) + lane] = f2bf(tile[lane][px]);
    }
}

// ---------------------------------------------------------------------------
// K2 v18 (= proven v16 + s_setprio around MFMA clusters).
//   R10 post-mortem: v17 (full-window + aliased sOff) made the compiler
//   demote the 16-uint4+8-Bfrag gather pipeline to SCRATCH (WRITE 33->223MB,
//   FETCH 7.6->157MB, VGPR 84, k2 238us). Twice now (R7, R10) structural
//   edits flipped regalloc into spills — v16/v13 shapes are the stable
//   optima. REVERT to R8's v16 (best: k2 135.5, e2e 273.1) byte-identical,
//   plus ONE orthogonal low-risk lever: __builtin_amdgcn_s_setprio(1)
//   around the MFMA clusters (gather PROC pair, offconv MFMA pair). T5
//   mechanism: 3 unsynchronized blocks/CU at staggered phases -> priority
//   keeps the matrix pipe fed while other blocks issue staging VALU.
//   Structure (v16): half-channel window passes, 36864B arena, 3 blocks/CU,
//   LDS window gather + XOR swizzle, far-bit global fallback, B-frag reg
//   pipeline, XCD swizzle b=bid&7, D-scrambled epilogue, f16 sWp, 27-row
//   sOff, __launch_bounds__(256,3).
// ---------------------------------------------------------------------------
__global__ __launch_bounds__(256, 3) void k2_fused(Params p) {
    __shared__ __align__(16) unsigned char arena[36864];
    // win:   [0, 20480)      bf16 [5][64px][32ch], byte=((r*64+px)<<6)+seg*16 ^ ((px&7)<<4)
    // sA:    [20480, 25088)  uint2 [9][64]  packed clamped pix (+far bit31 in .x)
    // sWp:   [25088, 29696)  f16x4 [9][64]  folded bilinear weights
    // sOff:  [29696, 36824)  f32 [27][66]
    uint2* sA   = (uint2*)(arena + 20480);
    f16x4* sWp  = (f16x4*)(arena + 25088);
    float* sOff = (float*)(arena + 29696);

    int bid = blockIdx.x;
    // XCD-aware decode: same-b blocks share an XCD's L2.
    int b = bid & 7; int gate = (bid >> 3) & 3; int row = bid >> 5;
    int t = threadIdx.x; int l = t & 63; int w = t >> 6;
    int q = l >> 4; int n = l & 15;
    int pxl = w * 16 + n;

    const unsigned short* wBp = (const unsigned short*)(p.ws + WS_WB);
    const unsigned short* owb = (const unsigned short*)(p.ws + WS_OWB);

    // per-lane gather address bias: byte = (pix<<6) + qb, then ^ ((pix&7)<<4)
    int qb = q * 16 - (row - 2) * 4096;

    f32x4 acc[4];
#pragma unroll
    for (int ot = 0; ot < 4; ++ot) acc[ot] = (f32x4){0.f, 0.f, 0.f, 0.f};

    for (int sub = 0; sub < 2; ++sub) {
        int br = gate * 2 + sub;
        const unsigned short* inT =
            (const unsigned short*)(p.ws + (sub ? WS_HT : WS_XT)) + ((size_t)b << 18);
        const float* obp = p.ws + WS_OB + br * 27;

        // ---- stage one 32-ch half of the 5-row window (zero-filled OOB) ----
        auto stage_half = [&](int half) {
#pragma unroll
            for (int it = 0; it < 5; ++it) {
                int u = t + it * 256;                  // u in [0,1280)
                int r = u >> 8; int px = (u >> 2) & 63; int seg = u & 3;
                int grow = row - 2 + r;
                uint4 v = {0u, 0u, 0u, 0u};
                if ((unsigned)grow < 64u)
                    v = *(const uint4*)(inT + (((size_t)grow * 64 + px) << 6) + half * 32 + seg * 8);
                unsigned byte = ((unsigned)u << 4) ^ (((unsigned)px & 7u) << 4);
                *(uint4*)(arena + byte) = v;
            }
        };

        // ---- offset-conv helpers: slice sl in [0,9): dy=sl/3, dxk=sl%3 ----
        auto loadA_oc = [&](int sl) -> bf16x8 {
            int dy = sl / 3; int dxk = sl % 3;
            int spx = pxl + dxk - 1;                  // [-1, 64]
            int spc = min(max(spx, 0), 63);
            unsigned byte = ((unsigned)((((dy + 1) * 64 + spc) << 6) + q * 16))
                            ^ (((unsigned)spc & 7u) << 4);
            bf16x8 af = *(const bf16x8*)(arena + byte);
            if ((unsigned)spx >= 64u) {               // zero halo columns
#pragma unroll
                for (int z = 0; z < 8; ++z) af[z] = (__bf16)0.f;
            }
            return af;
        };
        auto loadB_oc = [&](int sl, int half, int ot) -> bf16x8 {
            int dy = sl / 3; int dxk = sl % 3; int s = dxk * 2 + half;
            int kb = (br * 72 + dy * 24 + s * 4 + q) * 32;
            return *(const bf16x8*)(owb + (size_t)(kb + ot * 16 + n) * 8);
        };
        auto offconv_pass = [&](int half, f32x4& cA, f32x4& cB) {
            bf16x8 a0 = loadA_oc(0), b0 = loadB_oc(0, half, 0), b1 = loadB_oc(0, half, 1);
#pragma unroll 1
            for (int sl = 0; sl < 9; ++sl) {
                bf16x8 na = a0, nb0 = b0, nb1 = b1;
                if (sl < 8) {
                    na = loadA_oc(sl + 1); nb0 = loadB_oc(sl + 1, half, 0); nb1 = loadB_oc(sl + 1, half, 1);
                }
                __builtin_amdgcn_s_setprio(1);
                cA = __builtin_amdgcn_mfma_f32_16x16x32_bf16(a0, b0, cA, 0, 0, 0);
                cB = __builtin_amdgcn_mfma_f32_16x16x32_bf16(a0, b1, cB, 0, 0, 0);
                __builtin_amdgcn_s_setprio(0);
                a0 = na; b0 = nb0; b1 = nb1;
            }
        };

        f32x4 c0 = (f32x4){0.f,0.f,0.f,0.f}, c1 = (f32x4){0.f,0.f,0.f,0.f};
        f32x4 c2 = (f32x4){0.f,0.f,0.f,0.f}, c3 = (f32x4){0.f,0.f,0.f,0.f};

        __syncthreads();           // window/sA/sWp free (prev sub done)
        stage_half(0);
        __syncthreads();
        offconv_pass(0, c0, c1);   // s even K-slices (ch 0..31)
        __syncthreads();           // all waves done reading half-0 window
        stage_half(1);
        __syncthreads();
        offconv_pass(1, c2, c3);   // s odd K-slices (ch 32..63)

        f32x4 acc2[2];
        acc2[0] = c0 + c2;
        acc2[1] = c1 + c3;

        // D-frags (+bias) -> sOff[j][px]; j=ot*16+n, px=w*16+q*4+r; j<27 only
#pragma unroll
        for (int ot = 0; ot < 2; ++ot) {
            int j = ot * 16 + n;
            if (j < 27) {
                float bias = obp[j];
#pragma unroll
                for (int r = 0; r < 4; ++r)
                    sOff[j * 66 + w * 16 + q * 4 + r] = acc2[ot][r] + bias;
            }
        }
        __syncthreads();   // sOff visible

        // ---- Phase A: bilinear coords + (mask*inbound)-folded weights ----
        for (int i2 = t; i2 < 576; i2 += 256) {
            int px = i2 & 63; int k = i2 >> 6;
            float dy = sOff[(2 * k) * 66 + px];
            float dx = sOff[(2 * k + 1) * 66 + px];
            float mm = sOff[(18 + k) * 66 + px];
            float m = sigf(mm);
            int ki = k / 3, kj = k % 3;
            float py  = (float)(row + ki - 1) + dy;
            float pxx = (float)(px + kj - 1) + dx;
            float y0f = floorf(py), x0f = floorf(pxx);
            float wy = py - y0f, wx = pxx - x0f;
            int y0 = (int)y0f, x0 = (int)x0f;
            float y0i = ((unsigned)y0 < 64u) ? 1.f : 0.f;
            float y1i = ((unsigned)(y0 + 1) < 64u) ? 1.f : 0.f;
            float x0i = ((unsigned)x0 < 64u) ? 1.f : 0.f;
            float x1i = ((unsigned)(x0 + 1) < 64u) ? 1.f : 0.f;
            float w00 = (1.f - wy) * (1.f - wx) * m * y0i * x0i;
            float w01 = (1.f - wy) * wx         * m * y0i * x1i;
            float w10 = wy         * (1.f - wx) * m * y1i * x0i;
            float w11 = wy         * wx         * m * y1i * x1i;
            int cy0 = min(max(y0, 0), 63),     cy1 = min(max(y0 + 1, 0), 63);
            int cx0 = min(max(x0, 0), 63),     cx1 = min(max(x0 + 1, 0), 63);
            // far: clamped corner row outside staged window [row-2, row+2]
            int s0 = cy0 - (row - 2); int s1 = cy1 - (row - 2);
            unsigned farb = (((unsigned)s0 > 4u) || ((unsigned)s1 > 4u)) ? 0x80000000u : 0u;
            sA[k * 64 + px] = make_uint2(((unsigned)(cy0 * 64 + cx0) | ((unsigned)(cy0 * 64 + cx1) << 16)) | farb,
                                         (unsigned)(cy1 * 64 + cx0) | ((unsigned)(cy1 * 64 + cx1) << 16));
            sWp[k * 64 + px] = (f16x4){(_Float16)w00, (_Float16)w01, (_Float16)w10, (_Float16)w11};
        }
        __syncthreads();

        // ---- per-half pipelined LDS gather + B-frag register pipeline ----
        auto loadB_mn = [&](int S, int ot) -> bf16x8 {
            int kb = (br * 72 + S * 4 + q) * 64;
            return *(const bf16x8*)(wBp + (size_t)(kb + ot * 16 + n) * 8);
        };

#define PROC(Ca, Cb, Cc, Cd, WV, Wa, Wb, Wc, Wd)                               \
        {                                                                      \
            float sacc[8];                                                     \
            sacc[0] = WV.x * blo(Ca.x); sacc[1] = WV.x * bhi(Ca.x);            \
            sacc[2] = WV.x * blo(Ca.y); sacc[3] = WV.x * bhi(Ca.y);            \
            sacc[4] = WV.x * blo(Ca.z); sacc[5] = WV.x * bhi(Ca.z);            \
            sacc[6] = WV.x * blo(Ca.w); sacc[7] = WV.x * bhi(Ca.w);            \
            sacc[0] += WV.y * blo(Cb.x); sacc[1] += WV.y * bhi(Cb.x);          \
            sacc[2] += WV.y * blo(Cb.y); sacc[3] += WV.y * bhi(Cb.y);          \
            sacc[4] += WV.y * blo(Cb.z); sacc[5] += WV.y * bhi(Cb.z);          \
            sacc[6] += WV.y * blo(Cb.w); sacc[7] += WV.y * bhi(Cb.w);          \
            sacc[0] += WV.z * blo(Cc.x); sacc[1] += WV.z * bhi(Cc.x);          \
            sacc[2] += WV.z * blo(Cc.y); sacc[3] += WV.z * bhi(Cc.y);          \
            sacc[4] += WV.z * blo(Cc.z); sacc[5] += WV.z * bhi(Cc.z);          \
            sacc[6] += WV.z * blo(Cc.w); sacc[7] += WV.z * bhi(Cc.w);          \
            sacc[0] += WV.w * blo(Cd.x); sacc[1] += WV.w * bhi(Cd.x);          \
            sacc[2] += WV.w * blo(Cd.y); sacc[3] += WV.w * bhi(Cd.y);          \
            sacc[4] += WV.w * blo(Cd.z); sacc[5] += WV.w * bhi(Cd.z);          \
            sacc[6] += WV.w * blo(Cd.w); sacc[7] += WV.w * bhi(Cd.w);          \
            bf16x8 af;                                                         \
            _Pragma("unroll")                                                  \
            for (int j = 0; j < 8; ++j) af[j] = (__bf16)sacc[j];               \
            __builtin_amdgcn_s_setprio(1);                                     \
            acc[0] = __builtin_amdgcn_mfma_f32_16x16x32_bf16(af, Wa, acc[0], 0, 0, 0); \
            acc[1] = __builtin_amdgcn_mfma_f32_16x16x32_bf16(af, Wb, acc[1], 0, 0, 0); \
            acc[2] = __builtin_amdgcn_mfma_f32_16x16x32_bf16(af, Wc, acc[2], 0, 0, 0); \
            acc[3] = __builtin_amdgcn_mfma_f32_16x16x32_bf16(af, Wd, acc[3], 0, 0, 0); \
            __builtin_amdgcn_s_setprio(0);                                     \
        }

        auto gather_pass = [&](int half) {
            const unsigned short* cbaseh = inT + q * 8 + half * 32;
            // prologue: tap 0 addresses, corner LDS loads, tap-0 B-frags
            uint2 aa = sA[pxl];
            f16x4 wv4 = sWp[pxl];
            float4 wv = make_float4((float)wv4[0], (float)wv4[1], (float)wv4[2], (float)wv4[3]);
            unsigned p00 = aa.x & 0xFFFu, p01 = (aa.x >> 16) & 0xFFFu;
            unsigned p10 = aa.y & 0xFFFu, p11 = aa.y >> 16;
            unsigned a00 = (unsigned)(((int)(p00 << 6)) + qb) ^ ((p00 & 7u) << 4);
            unsigned a01 = (unsigned)(((int)(p01 << 6)) + qb) ^ ((p01 & 7u) << 4);
            unsigned a10 = (unsigned)(((int)(p10 << 6)) + qb) ^ ((p10 & 7u) << 4);
            unsigned a11 = (unsigned)(((int)(p11 << 6)) + qb) ^ ((p11 & 7u) << 4);
            uint4 Ca = *(const uint4*)(arena + a00);
            uint4 Cb = *(const uint4*)(arena + a01);
            uint4 Cc = *(const uint4*)(arena + a10);
            uint4 Cd = *(const uint4*)(arena + a11);
            if (aa.x & 0x80000000u) {   // rare: window miss -> exact global path
                Ca = *(const uint4*)(cbaseh + (p00 << 6));
                Cb = *(const uint4*)(cbaseh + (p01 << 6));
                Cc = *(const uint4*)(cbaseh + (p10 << 6));
                Cd = *(const uint4*)(cbaseh + (p11 << 6));
            }
            bf16x8 Ba = loadB_mn(half, 0), Bb = loadB_mn(half, 1);
            bf16x8 Bc = loadB_mn(half, 2), Bd = loadB_mn(half, 3);
#pragma unroll 1
            for (int ktap = 0; ktap < 9; ++ktap) {
                uint4 Na = Ca, Nb = Cb, Nc = Cc, Nd = Cd;
                float4 wvn = wv;
                bf16x8 nBa = Ba, nBb = Bb, nBc = Bc, nBd = Bd;
                if (ktap < 8) {   // prefetch next tap: A corners (LDS) + B (global)
                    uint2 aan = sA[(ktap + 1) * 64 + pxl];
                    f16x4 wvn4 = sWp[(ktap + 1) * 64 + pxl];
                    wvn = make_float4((float)wvn4[0], (float)wvn4[1], (float)wvn4[2], (float)wvn4[3]);
                    unsigned q00 = aan.x & 0xFFFu, q01 = (aan.x >> 16) & 0xFFFu;
                    unsigned q10 = aan.y & 0xFFFu, q11 = aan.y >> 16;
                    unsigned b00 = (unsigned)(((int)(q00 << 6)) + qb) ^ ((q00 & 7u) << 4);
                    unsigned b01 = (unsigned)(((int)(q01 << 6)) + qb) ^ ((q01 & 7u) << 4);
                    unsigned b10 = (unsigned)(((int)(q10 << 6)) + qb) ^ ((q10 & 7u) << 4);
                    unsigned b11 = (unsigned)(((int)(q11 << 6)) + qb) ^ ((q11 & 7u) << 4);
                    Na = *(const uint4*)(arena + b00);
                    Nb = *(const uint4*)(arena + b01);
                    Nc = *(const uint4*)(arena + b10);
                    Nd = *(const uint4*)(arena + b11);
                    if (aan.x & 0x80000000u) {
                        Na = *(const uint4*)(cbaseh + (q00 << 6));
                        Nb = *(const uint4*)(cbaseh + (q01 << 6));
                        Nc = *(const uint4*)(cbaseh + (q10 << 6));
                        Nd = *(const uint4*)(cbaseh + (q11 << 6));
                    }
                    nBa = loadB_mn((ktap + 1) * 2 + half, 0);
                    nBb = loadB_mn((ktap + 1) * 2 + half, 1);
                    nBc = loadB_mn((ktap + 1) * 2 + half, 2);
                    nBd = loadB_mn((ktap + 1) * 2 + half, 3);
                }
                PROC(Ca, Cb, Cc, Cd, wv, Ba, Bb, Bc, Bd)
                Ca = Na; Cb = Nb; Cc = Nc; Cd = Nd;
                Ba = nBa; Bb = nBb; Bc = nBc; Bd = nBd;
                wv = wvn;
            }
        };

        gather_pass(1);            // window currently holds half-1
        __syncthreads();           // all waves done reading half-1 window
        stage_half(0);
        __syncthreads();
        gather_pass(0);
#undef PROC
    }

    // epilogue: direct D-scrambled coalesced store; K3 decodes.
    float* gp = p.ws + WS_GATES + ((size_t)((gate * 8 + b) * 64 + row) << 12);
#pragma unroll
    for (int ot = 0; ot < 4; ++ot)
        *(float4*)(gp + ((w * 4 + ot) * 64 + l) * 4) = *(float4*)&acc[ot];
}

// ---------------------------------------------------------------------------
// K3: pointwise ConvLSTM combine, reading D-scrambled gates (coalesced) and
//   decoding (o,px) for c/out access (16B-segment granularity).
//   grid: 8192 blocks of 256.
// ---------------------------------------------------------------------------
__global__ __launch_bounds__(256) void k3_lstm(Params p) {
    int T = blockIdx.x * 256 + threadIdx.x;        // [b][row][i] over scrambled
    int i = T & 4095; int row = (T >> 12) & 63; int b = T >> 18;
    const float* gp = p.ws + WS_GATES;
    size_t base = ((size_t)(b * 64 + row) << 12) + i;
    float gi = gp[base];
    float gf = gp[base + 1 * PLANE];
    float gc = gp[base + 2 * PLANE];
    float go = gp[base + 3 * PLANE];
    // decode scramble: i = ((w*4+ot)*64 + l)*4 + r
    int r = i & 3; int l = (i >> 2) & 63; int u = i >> 8;
    int w = u >> 2; int ot = u & 3;
    int o = ot * 16 + (l & 15);
    int px = w * 16 + (l >> 4) * 4 + r;
    size_t cidx = ((size_t)(b * 64 + o) << 12) + row * 64 + px;
    float cold = p.c[cidx];
    float ig = sigf(gi + cold * p.wci[o] + p.bi[o]);
    float fg = sigf(gf + cold * p.wcf[o] + p.bf[o]);
    float cn = fg * cold + ig * tanhfast(gc + p.bc[o]);
    float og = sigf(go + cn * p.wco[o] + p.bo[o]);
    p.out[cidx] = og * tanhfast(cn);
    p.out[cidx + PLANE] = cn;
}

// ---------------------------------------------------------------------------
extern "C" void kernel_launch(void* const* d_in, const int* in_sizes, int n_in,
                              void* d_out, int out_size, void* d_ws, size_t ws_size,
                              hipStream_t stream) {
    (void)in_sizes; (void)n_in; (void)out_size; (void)ws_size;
    Params P;
    P.x = (const float*)d_in[0];
    P.h = (const float*)d_in[1];
    P.c = (const float*)d_in[2];
    for (int i = 0; i < 8; ++i) {
        P.w[i]  = (const float*)d_in[3 + 3 * i];
        P.ow[i] = (const float*)d_in[4 + 3 * i];
        P.ob[i] = (const float*)d_in[5 + 3 * i];
    }
    P.bi  = (const float*)d_in[27];
    P.bf  = (const float*)d_in[28];
    P.bc  = (const float*)d_in[29];
    P.bo  = (const float*)d_in[30];
    P.wci = (const float*)d_in[31];
    P.wcf = (const float*)d_in[32];
    P.wco = (const float*)d_in[33];
    P.out = (float*)d_out;
    P.ws  = (float*)d_ws;

    k0_prep   <<<dim3(2753), dim3(256), 0, stream>>>(P);
    k2_fused  <<<dim3(2048), dim3(256), 0, stream>>>(P);
    k3_lstm   <<<dim3(8192), dim3(256), 0, stream>>>(P);
}

// Round 12
// 269.423 us; speedup vs baseline: 1.4137x; 1.0195x over previous
//
#include <hip/hip_runtime.h>
#include <math.h>

// Problem constants (B=8, Cin=Cout=64, H=W=64, 3x3 kernel pad 1)
#define NB     8
#define NC     64
#define HW     4096           // 64*64
#define PLANE  2097152        // NB*NC*HW

// Workspace layout (float-slot offsets)
#define WS_WB     0           // f16 wB[8][72][64][8]   (294912 h = 147456 f)
#define WS_OWB    147456      // f16 owB[8][72][32][8]  (147456 h = 73728 f)
#define WS_OB     221184      // f32 obAll[8][27]
#define WS_GATES  221400      // f32 gates_scr[4][8][64][4096] = 8388608 (D-scrambled)
#define WS_XT     8610008     // f16 xT[8][4096][64] HWC  (1048576 f)
#define WS_HT     9658584     // f16 hT[8][4096][64] HWC  (1048576 f)
// total = 10707160 floats = 42.8 MB

typedef _Float16 f16x8 __attribute__((ext_vector_type(8)));
typedef _Float16 f16x4 __attribute__((ext_vector_type(4)));
typedef _Float16 f16x2 __attribute__((ext_vector_type(2)));
typedef float    f32x4 __attribute__((ext_vector_type(4)));

struct Params {
    const float* x; const float* h; const float* c;
    const float* w[8]; const float* ow[8]; const float* ob[8];
    const float* bi; const float* bf; const float* bc; const float* bo;
    const float* wci; const float* wcf; const float* wco;
    float* out; float* ws;
};

__device__ __forceinline__ float sigf(float v) { return 1.f / (1.f + __expf(-v)); }
__device__ __forceinline__ float tanhfast(float v) {
    return 1.f - 2.f / (__expf(2.f * v) + 1.f);
}
__device__ __forceinline__ unsigned short f2h(float v) {
    _Float16 h = (_Float16)v;
    return __builtin_bit_cast(unsigned short, h);
}
__device__ __forceinline__ f16x2 bch(unsigned d) { return __builtin_bit_cast(f16x2, d); }

// ---------------------------------------------------------------------------
// K0 (merged): weight B-frag packing + biases (blocks 0..1728), and
//   CHW fp32 -> HWC f16 transpose of x/h (blocks 1729..2752).
//   R12: all staged tensors/weights now F16 (10-bit mantissa, was bf16's 7)
//   so K2 can blend with packed v_pk_fma_f16 and feed mfma_*_f16 directly.
// ---------------------------------------------------------------------------
__global__ __launch_bounds__(256) void k0_prep(Params p) {
    if (blockIdx.x < 1729) {
        int i = blockIdx.x * 256 + threadIdx.x;
        unsigned short* wb  = (unsigned short*)(p.ws + WS_WB);
        unsigned short* owb = (unsigned short*)(p.ws + WS_OWB);
        if (i < 294912) {
            int br = i / 36864; int r = i % 36864;
            int kgrp = r >> 9; int o = (r >> 3) & 63; int j = r & 7;
            int k = kgrp * 8 + j;
            int ktap = k >> 6; int c = k & 63;
            wb[i] = f2h(p.w[br][(o * 64 + c) * 9 + ktap]);
        } else if (i < 294912 + 147456) {
            int ii = i - 294912;
            int br = ii / 18432; int r = ii % 18432;
            int kgrp = r >> 8; int o = (r >> 3) & 31; int j = r & 7;
            int k = kgrp * 8 + j;
            int ktap = k >> 6; int c = k & 63;
            float v = (o < 27) ? p.ow[br][(o * 64 + c) * 9 + ktap] : 0.f;
            owb[ii] = f2h(v);
        } else if (i < 294912 + 147456 + 216) {
            int ii = i - 442368;
            int br = ii / 27; int j = ii % 27;
            p.ws[WS_OB + ii] = p.ob[br][j];
        }
        return;
    }
    __shared__ float tile[64][65];
    int bid = blockIdx.x - 1729;
    int row = bid & 63; int b = (bid >> 6) & 7; int ten = bid >> 9;
    const float* src = ten ? p.h : p.x;
    unsigned short* dst = (unsigned short*)(p.ws + (ten ? WS_HT : WS_XT));
    int t = threadIdx.x; int lane = t & 63; int w4 = t >> 6;
#pragma unroll
    for (int i = 0; i < 16; ++i) {
        int c = i * 4 + w4;
        tile[c][lane] = src[((size_t)(b * 64 + c) << 12) + row * 64 + lane];
    }
    __syncthreads();
#pragma unroll
    for (int i = 0; i < 16; ++i) {
        int px = i * 4 + w4;
        dst[((size_t)(b * 4096 + row * 64 + px) << 6) + lane] = f2h(tile[lane][px]);
    }
}

// ---------------------------------------------------------------------------
// K2 v19 (= v16 structure + PACKED-F16 blend): offset-conv + deform + MFMA.
//   R11 post-mortem: plateau at ~135us is a VALU instruction-count floor —
//   the f32 bilinear blend (9.7 GFLOP grid-wide ~= 61us at 157TF) plus
//   bf16 unpack (blo/bhi) and f32->bf16 repack make PROC ~72 VALU insts;
//   VALUBusy 62% x 135us ~= 84us busy. Scheduling can't fix inst count.
//   THIS ROUND: stage x/h and weights as F16; blend with native packed-f16
//   vector math (f16x2 arithmetic -> v_pk_fma_f16, full-rate VOP3P):
//   per corner-dword 1 pk_fma replaces unpack+2fmac, result is already
//   packed f16 -> zero repack. PROC blend 72 -> ~20 insts. MFMA ->
//   mfma_f32_16x16x32_f16 (same shape/layout/rate). Precision IMPROVES
//   (f16 10-bit vs bf16 7-bit mantissa; data N(0,1), no range risk).
//   Register pressure drops (4x f16x2 acc vs 8x f32 sacc).
//   Structure identical to proven v16/v18: half-channel window passes,
//   36864B arena, 3 blocks/CU, LDS window gather + XOR swizzle, far-bit
//   global fallback, B-frag reg pipeline, XCD swizzle b=bid&7, f16 sWp,
//   27-row sOff, D-scrambled epilogue, setprio around MFMA (null but free).
// ---------------------------------------------------------------------------
__global__ __launch_bounds__(256, 3) void k2_fused(Params p) {
    __shared__ __align__(16) unsigned char arena[36864];
    // win:   [0, 20480)      f16 [5][64px][32ch], byte=((r*64+px)<<6)+seg*16 ^ ((px&7)<<4)
    // sA:    [20480, 25088)  uint2 [9][64]  packed clamped pix (+far bit31 in .x)
    // sWp:   [25088, 29696)  f16x4 [9][64]  folded bilinear weights
    // sOff:  [29696, 36824)  f32 [27][66]
    uint2* sA   = (uint2*)(arena + 20480);
    f16x4* sWp  = (f16x4*)(arena + 25088);
    float* sOff = (float*)(arena + 29696);

    int bid = blockIdx.x;
    // XCD-aware decode: same-b blocks share an XCD's L2.
    int b = bid & 7; int gate = (bid >> 3) & 3; int row = bid >> 5;
    int t = threadIdx.x; int l = t & 63; int w = t >> 6;
    int q = l >> 4; int n = l & 15;
    int pxl = w * 16 + n;

    const unsigned short* wBp = (const unsigned short*)(p.ws + WS_WB);
    const unsigned short* owb = (const unsigned short*)(p.ws + WS_OWB);

    // per-lane gather address bias: byte = (pix<<6) + qb, then ^ ((pix&7)<<4)
    int qb = q * 16 - (row - 2) * 4096;

    f32x4 acc[4];
#pragma unroll
    for (int ot = 0; ot < 4; ++ot) acc[ot] = (f32x4){0.f, 0.f, 0.f, 0.f};

    for (int sub = 0; sub < 2; ++sub) {
        int br = gate * 2 + sub;
        const unsigned short* inT =
            (const unsigned short*)(p.ws + (sub ? WS_HT : WS_XT)) + ((size_t)b << 18);
        const float* obp = p.ws + WS_OB + br * 27;

        // ---- stage one 32-ch half of the 5-row window (zero-filled OOB) ----
        auto stage_half = [&](int half) {
#pragma unroll
            for (int it = 0; it < 5; ++it) {
                int u = t + it * 256;                  // u in [0,1280)
                int r = u >> 8; int px = (u >> 2) & 63; int seg = u & 3;
                int grow = row - 2 + r;
                uint4 v = {0u, 0u, 0u, 0u};
                if ((unsigned)grow < 64u)
                    v = *(const uint4*)(inT + (((size_t)grow * 64 + px) << 6) + half * 32 + seg * 8);
                unsigned byte = ((unsigned)u << 4) ^ (((unsigned)px & 7u) << 4);
                *(uint4*)(arena + byte) = v;
            }
        };

        // ---- offset-conv helpers: slice sl in [0,9): dy=sl/3, dxk=sl%3 ----
        auto loadA_oc = [&](int sl) -> f16x8 {
            int dy = sl / 3; int dxk = sl % 3;
            int spx = pxl + dxk - 1;                  // [-1, 64]
            int spc = min(max(spx, 0), 63);
            unsigned byte = ((unsigned)((((dy + 1) * 64 + spc) << 6) + q * 16))
                            ^ (((unsigned)spc & 7u) << 4);
            f16x8 af = *(const f16x8*)(arena + byte);
            if ((unsigned)spx >= 64u) {               // zero halo columns
#pragma unroll
                for (int z = 0; z < 8; ++z) af[z] = (_Float16)0.f;
            }
            return af;
        };
        auto loadB_oc = [&](int sl, int half, int ot) -> f16x8 {
            int dy = sl / 3; int dxk = sl % 3; int s = dxk * 2 + half;
            int kb = (br * 72 + dy * 24 + s * 4 + q) * 32;
            return *(const f16x8*)(owb + (size_t)(kb + ot * 16 + n) * 8);
        };
        auto offconv_pass = [&](int half, f32x4& cA, f32x4& cB) {
            f16x8 a0 = loadA_oc(0), b0 = loadB_oc(0, half, 0), b1 = loadB_oc(0, half, 1);
#pragma unroll 1
            for (int sl = 0; sl < 9; ++sl) {
                f16x8 na = a0, nb0 = b0, nb1 = b1;
                if (sl < 8) {
                    na = loadA_oc(sl + 1); nb0 = loadB_oc(sl + 1, half, 0); nb1 = loadB_oc(sl + 1, half, 1);
                }
                __builtin_amdgcn_s_setprio(1);
                cA = __builtin_amdgcn_mfma_f32_16x16x32_f16(a0, b0, cA, 0, 0, 0);
                cB = __builtin_amdgcn_mfma_f32_16x16x32_f16(a0, b1, cB, 0, 0, 0);
                __builtin_amdgcn_s_setprio(0);
                a0 = na; b0 = nb0; b1 = nb1;
            }
        };

        f32x4 c0 = (f32x4){0.f,0.f,0.f,0.f}, c1 = (f32x4){0.f,0.f,0.f,0.f};
        f32x4 c2 = (f32x4){0.f,0.f,0.f,0.f}, c3 = (f32x4){0.f,0.f,0.f,0.f};

        __syncthreads();           // window/sA/sWp free (prev sub done)
        stage_half(0);
        __syncthreads();
        offconv_pass(0, c0, c1);   // s even K-slices (ch 0..31)
        __syncthreads();           // all waves done reading half-0 window
        stage_half(1);
        __syncthreads();
        offconv_pass(1, c2, c3);   // s odd K-slices (ch 32..63)

        f32x4 acc2[2];
        acc2[0] = c0 + c2;
        acc2[1] = c1 + c3;

        // D-frags (+bias) -> sOff[j][px]; j=ot*16+n, px=w*16+q*4+r; j<27 only
#pragma unroll
        for (int ot = 0; ot < 2; ++ot) {
            int j = ot * 16 + n;
            if (j < 27) {
                float bias = obp[j];
#pragma unroll
                for (int r = 0; r < 4; ++r)
                    sOff[j * 66 + w * 16 + q * 4 + r] = acc2[ot][r] + bias;
            }
        }
        __syncthreads();   // sOff visible

        // ---- Phase A: bilinear coords + (mask*inbound)-folded weights ----
        for (int i2 = t; i2 < 576; i2 += 256) {
            int px = i2 & 63; int k = i2 >> 6;
            float dy = sOff[(2 * k) * 66 + px];
            float dx = sOff[(2 * k + 1) * 66 + px];
            float mm = sOff[(18 + k) * 66 + px];
            float m = sigf(mm);
            int ki = k / 3, kj = k % 3;
            float py  = (float)(row + ki - 1) + dy;
            float pxx = (float)(px + kj - 1) + dx;
            float y0f = floorf(py), x0f = floorf(pxx);
            float wy = py - y0f, wx = pxx - x0f;
            int y0 = (int)y0f, x0 = (int)x0f;
            float y0i = ((unsigned)y0 < 64u) ? 1.f : 0.f;
            float y1i = ((unsigned)(y0 + 1) < 64u) ? 1.f : 0.f;
            float x0i = ((unsigned)x0 < 64u) ? 1.f : 0.f;
            float x1i = ((unsigned)(x0 + 1) < 64u) ? 1.f : 0.f;
            float w00 = (1.f - wy) * (1.f - wx) * m * y0i * x0i;
            float w01 = (1.f - wy) * wx         * m * y0i * x1i;
            float w10 = wy         * (1.f - wx) * m * y1i * x0i;
            float w11 = wy         * wx         * m * y1i * x1i;
            int cy0 = min(max(y0, 0), 63),     cy1 = min(max(y0 + 1, 0), 63);
            int cx0 = min(max(x0, 0), 63),     cx1 = min(max(x0 + 1, 0), 63);
            // far: clamped corner row outside staged window [row-2, row+2]
            int s0 = cy0 - (row - 2); int s1 = cy1 - (row - 2);
            unsigned farb = (((unsigned)s0 > 4u) || ((unsigned)s1 > 4u)) ? 0x80000000u : 0u;
            sA[k * 64 + px] = make_uint2(((unsigned)(cy0 * 64 + cx0) | ((unsigned)(cy0 * 64 + cx1) << 16)) | farb,
                                         (unsigned)(cy1 * 64 + cx0) | ((unsigned)(cy1 * 64 + cx1) << 16));
            sWp[k * 64 + px] = (f16x4){(_Float16)w00, (_Float16)w01, (_Float16)w10, (_Float16)w11};
        }
        __syncthreads();

        // ---- per-half pipelined LDS gather + B-frag register pipeline ----
        auto loadB_mn = [&](int S, int ot) -> f16x8 {
            int kb = (br * 72 + S * 4 + q) * 64;
            return *(const f16x8*)(wBp + (size_t)(kb + ot * 16 + n) * 8);
        };

        // Packed-f16 blend: per corner-dword one v_pk_fma_f16; af is
        // already packed f16 (no unpack, no repack).
#define PROC(Ca, Cb, Cc, Cd, WV, Wa, Wb, Wc, Wd)                               \
        {                                                                      \
            f16x2 pw0 = (f16x2){WV[0], WV[0]};                                 \
            f16x2 pw1 = (f16x2){WV[1], WV[1]};                                 \
            f16x2 pw2 = (f16x2){WV[2], WV[2]};                                 \
            f16x2 pw3 = (f16x2){WV[3], WV[3]};                                 \
            f16x2 a0 = bch(Ca.x) * pw0 + bch(Cb.x) * pw1                       \
                     + bch(Cc.x) * pw2 + bch(Cd.x) * pw3;                      \
            f16x2 a1 = bch(Ca.y) * pw0 + bch(Cb.y) * pw1                       \
                     + bch(Cc.y) * pw2 + bch(Cd.y) * pw3;                      \
            f16x2 a2 = bch(Ca.z) * pw0 + bch(Cb.z) * pw1                       \
                     + bch(Cc.z) * pw2 + bch(Cd.z) * pw3;                      \
            f16x2 a3 = bch(Ca.w) * pw0 + bch(Cb.w) * pw1                       \
                     + bch(Cc.w) * pw2 + bch(Cd.w) * pw3;                      \
            f16x8 af = (f16x8){a0[0], a0[1], a1[0], a1[1],                     \
                               a2[0], a2[1], a3[0], a3[1]};                    \
            __builtin_amdgcn_s_setprio(1);                                     \
            acc[0] = __builtin_amdgcn_mfma_f32_16x16x32_f16(af, Wa, acc[0], 0, 0, 0); \
            acc[1] = __builtin_amdgcn_mfma_f32_16x16x32_f16(af, Wb, acc[1], 0, 0, 0); \
            acc[2] = __builtin_amdgcn_mfma_f32_16x16x32_f16(af, Wc, acc[2], 0, 0, 0); \
            acc[3] = __builtin_amdgcn_mfma_f32_16x16x32_f16(af, Wd, acc[3], 0, 0, 0); \
            __builtin_amdgcn_s_setprio(0);                                     \
        }

        auto gather_pass = [&](int half) {
            const unsigned short* cbaseh = inT + q * 8 + half * 32;
            // prologue: tap 0 addresses, corner LDS loads, tap-0 B-frags
            uint2 aa = sA[pxl];
            f16x4 wv = sWp[pxl];
            unsigned p00 = aa.x & 0xFFFu, p01 = (aa.x >> 16) & 0xFFFu;
            unsigned p10 = aa.y & 0xFFFu, p11 = aa.y >> 16;
            unsigned a00 = (unsigned)(((int)(p00 << 6)) + qb) ^ ((p00 & 7u) << 4);
            unsigned a01 = (unsigned)(((int)(p01 << 6)) + qb) ^ ((p01 & 7u) << 4);
            unsigned a10 = (unsigned)(((int)(p10 << 6)) + qb) ^ ((p10 & 7u) << 4);
            unsigned a11 = (unsigned)(((int)(p11 << 6)) + qb) ^ ((p11 & 7u) << 4);
            uint4 Ca = *(const uint4*)(arena + a00);
            uint4 Cb = *(const uint4*)(arena + a01);
            uint4 Cc = *(const uint4*)(arena + a10);
            uint4 Cd = *(const uint4*)(arena + a11);
            if (aa.x & 0x80000000u) {   // rare: window miss -> exact global path
                Ca = *(const uint4*)(cbaseh + (p00 << 6));
                Cb = *(const uint4*)(cbaseh + (p01 << 6));
                Cc = *(const uint4*)(cbaseh + (p10 << 6));
                Cd = *(const uint4*)(cbaseh + (p11 << 6));
            }
            f16x8 Ba = loadB_mn(half, 0), Bb = loadB_mn(half, 1);
            f16x8 Bc = loadB_mn(half, 2), Bd = loadB_mn(half, 3);
#pragma unroll 1
            for (int ktap = 0; ktap < 9; ++ktap) {
                uint4 Na = Ca, Nb = Cb, Nc = Cc, Nd = Cd;
                f16x4 wvn = wv;
                f16x8 nBa = Ba, nBb = Bb, nBc = Bc, nBd = Bd;
                if (ktap < 8) {   // prefetch next tap: A corners (LDS) + B (global)
                    uint2 aan = sA[(ktap + 1) * 64 + pxl];
                    wvn = sWp[(ktap + 1) * 64 + pxl];
                    unsigned q00 = aan.x & 0xFFFu, q01 = (aan.x >> 16) & 0xFFFu;
                    unsigned q10 = aan.y & 0xFFFu, q11 = aan.y >> 16;
                    unsigned b00 = (unsigned)(((int)(q00 << 6)) + qb) ^ ((q00 & 7u) << 4);
                    unsigned b01 = (unsigned)(((int)(q01 << 6)) + qb) ^ ((q01 & 7u) << 4);
                    unsigned b10 = (unsigned)(((int)(q10 << 6)) + qb) ^ ((q10 & 7u) << 4);
                    unsigned b11 = (unsigned)(((int)(q11 << 6)) + qb) ^ ((q11 & 7u) << 4);
                    Na = *(const uint4*)(arena + b00);
                    Nb = *(const uint4*)(arena + b01);
                    Nc = *(const uint4*)(arena + b10);
                    Nd = *(const uint4*)(arena + b11);
                    if (aan.x & 0x80000000u) {
                        Na = *(const uint4*)(cbaseh + (q00 << 6));
                        Nb = *(const uint4*)(cbaseh + (q01 << 6));
                        Nc = *(const uint4*)(cbaseh + (q10 << 6));
                        Nd = *(const uint4*)(cbaseh + (q11 << 6));
                    }
                    nBa = loadB_mn((ktap + 1) * 2 + half, 0);
                    nBb = loadB_mn((ktap + 1) * 2 + half, 1);
                    nBc = loadB_mn((ktap + 1) * 2 + half, 2);
                    nBd = loadB_mn((ktap + 1) * 2 + half, 3);
                }
                PROC(Ca, Cb, Cc, Cd, wv, Ba, Bb, Bc, Bd)
                Ca = Na; Cb = Nb; Cc = Nc; Cd = Nd;
                Ba = nBa; Bb = nBb; Bc = nBc; Bd = nBd;
                wv = wvn;
            }
        };

        gather_pass(1);            // window currently holds half-1
        __syncthreads();           // all waves done reading half-1 window
        stage_half(0);
        __syncthreads();
        gather_pass(0);
#undef PROC
    }

    // epilogue: direct D-scrambled coalesced store; K3 decodes.
    float* gp = p.ws + WS_GATES + ((size_t)((gate * 8 + b) * 64 + row) << 12);
#pragma unroll
    for (int ot = 0; ot < 4; ++ot)
        *(float4*)(gp + ((w * 4 + ot) * 64 + l) * 4) = *(float4*)&acc[ot];
}

// ---------------------------------------------------------------------------
// K3: pointwise ConvLSTM combine, reading D-scrambled gates (coalesced) and
//   decoding (o,px) for c/out access (16B-segment granularity).
//   grid: 8192 blocks of 256.
// ---------------------------------------------------------------------------
__global__ __launch_bounds__(256) void k3_lstm(Params p) {
    int T = blockIdx.x * 256 + threadIdx.x;        // [b][row][i] over scrambled
    int i = T & 4095; int row = (T >> 12) & 63; int b = T >> 18;
    const float* gp = p.ws + WS_GATES;
    size_t base = ((size_t)(b * 64 + row) << 12) + i;
    float gi = gp[base];
    float gf = gp[base + 1 * PLANE];
    float gc = gp[base + 2 * PLANE];
    float go = gp[base + 3 * PLANE];
    // decode scramble: i = ((w*4+ot)*64 + l)*4 + r
    int r = i & 3; int l = (i >> 2) & 63; int u = i >> 8;
    int w = u >> 2; int ot = u & 3;
    int o = ot * 16 + (l & 15);
    int px = w * 16 + (l >> 4) * 4 + r;
    size_t cidx = ((size_t)(b * 64 + o) << 12) + row * 64 + px;
    float cold = p.c[cidx];
    float ig = sigf(gi + cold * p.wci[o] + p.bi[o]);
    float fg = sigf(gf + cold * p.wcf[o] + p.bf[o]);
    float cn = fg * cold + ig * tanhfast(gc + p.bc[o]);
    float og = sigf(go + cn * p.wco[o] + p.bo[o]);
    p.out[cidx] = og * tanhfast(cn);
    p.out[cidx + PLANE] = cn;
}

// ---------------------------------------------------------------------------
extern "C" void kernel_launch(void* const* d_in, const int* in_sizes, int n_in,
                              void* d_out, int out_size, void* d_ws, size_t ws_size,
                              hipStream_t stream) {
    (void)in_sizes; (void)n_in; (void)out_size; (void)ws_size;
    Params P;
    P.x = (const float*)d_in[0];
    P.h = (const float*)d_in[1];
    P.c = (const float*)d_in[2];
    for (int i = 0; i < 8; ++i) {
        P.w[i]  = (const float*)d_in[3 + 3 * i];
        P.ow[i] = (const float*)d_in[4 + 3 * i];
        P.ob[i] = (const float*)d_in[5 + 3 * i];
    }
    P.bi  = (const float*)d_in[27];
    P.bf  = (const float*)d_in[28];
    P.bc  = (const float*)d_in[29];
    P.bo  = (const float*)d_in[30];
    P.wci = (const float*)d_in[31];
    P.wcf = (const float*)d_in[32];
    P.wco = (const float*)d_in[33];
    P.out = (float*)d_out;
    P.ws  = (float*)d_ws;

    k0_prep   <<<dim3(2753), dim3(256), 0, stream>>>(P);
    k2_fused  <<<dim3(2048), dim3(256), 0, stream>>>(P);
    k3_lstm   <<<dim3(8192), dim3(256), 0, stream>>>(P);
}

// Round 13
// 232.739 us; speedup vs baseline: 1.6365x; 1.1576x over previous
//
#include <hip/hip_runtime.h>
#include <math.h>

// Problem constants (B=8, Cin=Cout=64, H=W=64, 3x3 kernel pad 1)
#define NB     8
#define NC     64
#define HW     4096           // 64*64
#define PLANE  2097152        // NB*NC*HW

// Workspace layout (float-slot offsets)
#define WS_WB     0           // f16 wB[8][72][64][8]   (294912 h = 147456 f)
#define WS_OWB    147456      // f16 owB[8][72][32][8]  (147456 h = 73728 f)
#define WS_OB     221184      // f32 obAll[8][27]
#define WS_GATES  221400      // f32 gates_scr[4][8][64][4096] = 8388608 (D-scrambled)
#define WS_XT     8610008     // f16 xT[8][4096][64] HWC  (1048576 f)
#define WS_HT     9658584     // f16 hT[8][4096][64] HWC  (1048576 f)
// total = 10707160 floats = 42.8 MB

typedef _Float16 f16x8 __attribute__((ext_vector_type(8)));
typedef _Float16 f16x4 __attribute__((ext_vector_type(4)));
typedef _Float16 f16x2 __attribute__((ext_vector_type(2)));
typedef float    f32x4 __attribute__((ext_vector_type(4)));

struct Params {
    const float* x; const float* h; const float* c;
    const float* w[8]; const float* ow[8]; const float* ob[8];
    const float* bi; const float* bf; const float* bc; const float* bo;
    const float* wci; const float* wcf; const float* wco;
    float* out; float* ws;
};

__device__ __forceinline__ float sigf(float v) { return 1.f / (1.f + __expf(-v)); }
__device__ __forceinline__ float tanhfast(float v) {
    return 1.f - 2.f / (__expf(2.f * v) + 1.f);
}
__device__ __forceinline__ unsigned short f2h(float v) {
    _Float16 h = (_Float16)v;
    return __builtin_bit_cast(unsigned short, h);
}
__device__ __forceinline__ f16x2 bch(unsigned d) { return __builtin_bit_cast(f16x2, d); }

// ---------------------------------------------------------------------------
// K0 (merged): weight B-frag packing + biases (blocks 0..1728), and
//   CHW fp32 -> HWC f16 transpose of x/h (blocks 1729..2752).
// ---------------------------------------------------------------------------
__global__ __launch_bounds__(256) void k0_prep(Params p) {
    if (blockIdx.x < 1729) {
        int i = blockIdx.x * 256 + threadIdx.x;
        unsigned short* wb  = (unsigned short*)(p.ws + WS_WB);
        unsigned short* owb = (unsigned short*)(p.ws + WS_OWB);
        if (i < 294912) {
            int br = i / 36864; int r = i % 36864;
            int kgrp = r >> 9; int o = (r >> 3) & 63; int j = r & 7;
            int k = kgrp * 8 + j;
            int ktap = k >> 6; int c = k & 63;
            wb[i] = f2h(p.w[br][(o * 64 + c) * 9 + ktap]);
        } else if (i < 294912 + 147456) {
            int ii = i - 294912;
            int br = ii / 18432; int r = ii % 18432;
            int kgrp = r >> 8; int o = (r >> 3) & 31; int j = r & 7;
            int k = kgrp * 8 + j;
            int ktap = k >> 6; int c = k & 63;
            float v = (o < 27) ? p.ow[br][(o * 64 + c) * 9 + ktap] : 0.f;
            owb[ii] = f2h(v);
        } else if (i < 294912 + 147456 + 216) {
            int ii = i - 442368;
            int br = ii / 27; int j = ii % 27;
            p.ws[WS_OB + ii] = p.ob[br][j];
        }
        return;
    }
    __shared__ float tile[64][65];
    int bid = blockIdx.x - 1729;
    int row = bid & 63; int b = (bid >> 6) & 7; int ten = bid >> 9;
    const float* src = ten ? p.h : p.x;
    unsigned short* dst = (unsigned short*)(p.ws + (ten ? WS_HT : WS_XT));
    int t = threadIdx.x; int lane = t & 63; int w4 = t >> 6;
#pragma unroll
    for (int i = 0; i < 16; ++i) {
        int c = i * 4 + w4;
        tile[c][lane] = src[((size_t)(b * 64 + c) << 12) + row * 64 + lane];
    }
    __syncthreads();
#pragma unroll
    for (int i = 0; i < 16; ++i) {
        int px = i * 4 + w4;
        dst[((size_t)(b * 4096 + row * 64 + px) << 6) + lane] = f2h(tile[lane][px]);
    }
}

// ---------------------------------------------------------------------------
// K2 v20 (= v19 + ping-pong unroll-2, no rotation copies): offset-conv +
//   deform + MFMA.
//   R12 post-mortem: packed-f16 blend cut VALUBusy 62->48.7 but dur only
//   -5.5%. Back-solve: ~9.4k VALU insts/wave vs ~5k useful — the excess is
//   the double-buffer ROTATION in both pipelined loops: `N=C; if(k<8)
//   N=load; ...; C=N` under #pragma unroll 1 forces ~34 VGPR movs/tap
//   (gather) and ~12/slice (offconv) plus the branch. THIS ROUND: manual
//   unroll-by-2 ping-pong (taps 0..8 = 4x2+1 peeled tail): every load
//   targets a fixed register set, every PROC reads a fixed set — no
//   conditionals, no copies. Live state identical -> low regalloc risk.
//   Numerics bit-identical to v19.
//   Structure (v16 skeleton): half-channel window passes, 36864B arena,
//   3 blocks/CU, LDS window gather + XOR swizzle, far-bit global fallback,
//   B-frag reg pipeline, XCD swizzle b=bid&7, f16 sWp, 27-row sOff,
//   D-scrambled epilogue, packed-f16 blend, setprio around MFMA.
// ---------------------------------------------------------------------------
__global__ __launch_bounds__(256, 3) void k2_fused(Params p) {
    __shared__ __align__(16) unsigned char arena[36864];
    // win:   [0, 20480)      f16 [5][64px][32ch], byte=((r*64+px)<<6)+seg*16 ^ ((px&7)<<4)
    // sA:    [20480, 25088)  uint2 [9][64]  packed clamped pix (+far bit31 in .x)
    // sWp:   [25088, 29696)  f16x4 [9][64]  folded bilinear weights
    // sOff:  [29696, 36824)  f32 [27][66]
    uint2* sA   = (uint2*)(arena + 20480);
    f16x4* sWp  = (f16x4*)(arena + 25088);
    float* sOff = (float*)(arena + 29696);

    int bid = blockIdx.x;
    // XCD-aware decode: same-b blocks share an XCD's L2.
    int b = bid & 7; int gate = (bid >> 3) & 3; int row = bid >> 5;
    int t = threadIdx.x; int l = t & 63; int w = t >> 6;
    int q = l >> 4; int n = l & 15;
    int pxl = w * 16 + n;

    const unsigned short* wBp = (const unsigned short*)(p.ws + WS_WB);
    const unsigned short* owb = (const unsigned short*)(p.ws + WS_OWB);

    // per-lane gather address bias: byte = (pix<<6) + qb, then ^ ((pix&7)<<4)
    int qb = q * 16 - (row - 2) * 4096;

    f32x4 acc[4];
#pragma unroll
    for (int ot = 0; ot < 4; ++ot) acc[ot] = (f32x4){0.f, 0.f, 0.f, 0.f};

    for (int sub = 0; sub < 2; ++sub) {
        int br = gate * 2 + sub;
        const unsigned short* inT =
            (const unsigned short*)(p.ws + (sub ? WS_HT : WS_XT)) + ((size_t)b << 18);
        const float* obp = p.ws + WS_OB + br * 27;

        // ---- stage one 32-ch half of the 5-row window (zero-filled OOB) ----
        auto stage_half = [&](int half) {
#pragma unroll
            for (int it = 0; it < 5; ++it) {
                int u = t + it * 256;                  // u in [0,1280)
                int r = u >> 8; int px = (u >> 2) & 63; int seg = u & 3;
                int grow = row - 2 + r;
                uint4 v = {0u, 0u, 0u, 0u};
                if ((unsigned)grow < 64u)
                    v = *(const uint4*)(inT + (((size_t)grow * 64 + px) << 6) + half * 32 + seg * 8);
                unsigned byte = ((unsigned)u << 4) ^ (((unsigned)px & 7u) << 4);
                *(uint4*)(arena + byte) = v;
            }
        };

        // ---- offset-conv helpers: slice sl in [0,9): dy=sl/3, dxk=sl%3 ----
        auto loadA_oc = [&](int sl) -> f16x8 {
            int dy = sl / 3; int dxk = sl % 3;
            int spx = pxl + dxk - 1;                  // [-1, 64]
            int spc = min(max(spx, 0), 63);
            unsigned byte = ((unsigned)((((dy + 1) * 64 + spc) << 6) + q * 16))
                            ^ (((unsigned)spc & 7u) << 4);
            f16x8 af = *(const f16x8*)(arena + byte);
            if ((unsigned)spx >= 64u) {               // zero halo columns
#pragma unroll
                for (int z = 0; z < 8; ++z) af[z] = (_Float16)0.f;
            }
            return af;
        };
        auto loadB_oc = [&](int sl, int half, int ot) -> f16x8 {
            int dy = sl / 3; int dxk = sl % 3; int s = dxk * 2 + half;
            int kb = (br * 72 + dy * 24 + s * 4 + q) * 32;
            return *(const f16x8*)(owb + (size_t)(kb + ot * 16 + n) * 8);
        };
        // ping-pong unroll-2 over 9 K-slices: no rotation copies, no branch.
        auto offconv_pass = [&](int half, f32x4& cA, f32x4& cB) {
            f16x8 a0 = loadA_oc(0), b0 = loadB_oc(0, half, 0), b1 = loadB_oc(0, half, 1);
            f16x8 a1, b2, b3;
#pragma unroll 1
            for (int s2 = 0; s2 < 4; ++s2) {
                a1 = loadA_oc(2 * s2 + 1);
                b2 = loadB_oc(2 * s2 + 1, half, 0);
                b3 = loadB_oc(2 * s2 + 1, half, 1);
                __builtin_amdgcn_s_setprio(1);
                cA = __builtin_amdgcn_mfma_f32_16x16x32_f16(a0, b0, cA, 0, 0, 0);
                cB = __builtin_amdgcn_mfma_f32_16x16x32_f16(a0, b1, cB, 0, 0, 0);
                __builtin_amdgcn_s_setprio(0);
                a0 = loadA_oc(2 * s2 + 2);
                b0 = loadB_oc(2 * s2 + 2, half, 0);
                b1 = loadB_oc(2 * s2 + 2, half, 1);
                __builtin_amdgcn_s_setprio(1);
                cA = __builtin_amdgcn_mfma_f32_16x16x32_f16(a1, b2, cA, 0, 0, 0);
                cB = __builtin_amdgcn_mfma_f32_16x16x32_f16(a1, b3, cB, 0, 0, 0);
                __builtin_amdgcn_s_setprio(0);
            }
            __builtin_amdgcn_s_setprio(1);
            cA = __builtin_amdgcn_mfma_f32_16x16x32_f16(a0, b0, cA, 0, 0, 0);
            cB = __builtin_amdgcn_mfma_f32_16x16x32_f16(a0, b1, cB, 0, 0, 0);
            __builtin_amdgcn_s_setprio(0);
        };

        f32x4 c0 = (f32x4){0.f,0.f,0.f,0.f}, c1 = (f32x4){0.f,0.f,0.f,0.f};
        f32x4 c2 = (f32x4){0.f,0.f,0.f,0.f}, c3 = (f32x4){0.f,0.f,0.f,0.f};

        __syncthreads();           // window/sA/sWp free (prev sub done)
        stage_half(0);
        __syncthreads();
        offconv_pass(0, c0, c1);   // s even K-slices (ch 0..31)
        __syncthreads();           // all waves done reading half-0 window
        stage_half(1);
        __syncthreads();
        offconv_pass(1, c2, c3);   // s odd K-slices (ch 32..63)

        f32x4 acc2[2];
        acc2[0] = c0 + c2;
        acc2[1] = c1 + c3;

        // D-frags (+bias) -> sOff[j][px]; j=ot*16+n, px=w*16+q*4+r; j<27 only
#pragma unroll
        for (int ot = 0; ot < 2; ++ot) {
            int j = ot * 16 + n;
            if (j < 27) {
                float bias = obp[j];
#pragma unroll
                for (int r = 0; r < 4; ++r)
                    sOff[j * 66 + w * 16 + q * 4 + r] = acc2[ot][r] + bias;
            }
        }
        __syncthreads();   // sOff visible

        // ---- Phase A: bilinear coords + (mask*inbound)-folded weights ----
        for (int i2 = t; i2 < 576; i2 += 256) {
            int px = i2 & 63; int k = i2 >> 6;
            float dy = sOff[(2 * k) * 66 + px];
            float dx = sOff[(2 * k + 1) * 66 + px];
            float mm = sOff[(18 + k) * 66 + px];
            float m = sigf(mm);
            int ki = k / 3, kj = k % 3;
            float py  = (float)(row + ki - 1) + dy;
            float pxx = (float)(px + kj - 1) + dx;
            float y0f = floorf(py), x0f = floorf(pxx);
            float wy = py - y0f, wx = pxx - x0f;
            int y0 = (int)y0f, x0 = (int)x0f;
            float y0i = ((unsigned)y0 < 64u) ? 1.f : 0.f;
            float y1i = ((unsigned)(y0 + 1) < 64u) ? 1.f : 0.f;
            float x0i = ((unsigned)x0 < 64u) ? 1.f : 0.f;
            float x1i = ((unsigned)(x0 + 1) < 64u) ? 1.f : 0.f;
            float w00 = (1.f - wy) * (1.f - wx) * m * y0i * x0i;
            float w01 = (1.f - wy) * wx         * m * y0i * x1i;
            float w10 = wy         * (1.f - wx) * m * y1i * x0i;
            float w11 = wy         * wx         * m * y1i * x1i;
            int cy0 = min(max(y0, 0), 63),     cy1 = min(max(y0 + 1, 0), 63);
            int cx0 = min(max(x0, 0), 63),     cx1 = min(max(x0 + 1, 0), 63);
            // far: clamped corner row outside staged window [row-2, row+2]
            int s0 = cy0 - (row - 2); int s1 = cy1 - (row - 2);
            unsigned farb = (((unsigned)s0 > 4u) || ((unsigned)s1 > 4u)) ? 0x80000000u : 0u;
            sA[k * 64 + px] = make_uint2(((unsigned)(cy0 * 64 + cx0) | ((unsigned)(cy0 * 64 + cx1) << 16)) | farb,
                                         (unsigned)(cy1 * 64 + cx0) | ((unsigned)(cy1 * 64 + cx1) << 16));
            sWp[k * 64 + px] = (f16x4){(_Float16)w00, (_Float16)w01, (_Float16)w10, (_Float16)w11};
        }
        __syncthreads();

        // ---- per-half pipelined LDS gather + B-frag register pipeline ----
        auto loadB_mn = [&](int S, int ot) -> f16x8 {
            int kb = (br * 72 + S * 4 + q) * 64;
            return *(const f16x8*)(wBp + (size_t)(kb + ot * 16 + n) * 8);
        };

        // Packed-f16 blend: per corner-dword one v_pk_fma_f16; af is
        // already packed f16 (no unpack, no repack).
#define PROC(Ca, Cb, Cc, Cd, WV, Wa, Wb, Wc, Wd)                               \
        {                                                                      \
            f16x2 pw0 = (f16x2){WV[0], WV[0]};                                 \
            f16x2 pw1 = (f16x2){WV[1], WV[1]};                                 \
            f16x2 pw2 = (f16x2){WV[2], WV[2]};                                 \
            f16x2 pw3 = (f16x2){WV[3], WV[3]};                                 \
            f16x2 a0 = bch(Ca.x) * pw0 + bch(Cb.x) * pw1                       \
                     + bch(Cc.x) * pw2 + bch(Cd.x) * pw3;                      \
            f16x2 a1 = bch(Ca.y) * pw0 + bch(Cb.y) * pw1                       \
                     + bch(Cc.y) * pw2 + bch(Cd.y) * pw3;                      \
            f16x2 a2 = bch(Ca.z) * pw0 + bch(Cb.z) * pw1                       \
                     + bch(Cc.z) * pw2 + bch(Cd.z) * pw3;                      \
            f16x2 a3 = bch(Ca.w) * pw0 + bch(Cb.w) * pw1                       \
                     + bch(Cc.w) * pw2 + bch(Cd.w) * pw3;                      \
            f16x8 af = (f16x8){a0[0], a0[1], a1[0], a1[1],                     \
                               a2[0], a2[1], a3[0], a3[1]};                    \
            __builtin_amdgcn_s_setprio(1);                                     \
            acc[0] = __builtin_amdgcn_mfma_f32_16x16x32_f16(af, Wa, acc[0], 0, 0, 0); \
            acc[1] = __builtin_amdgcn_mfma_f32_16x16x32_f16(af, Wb, acc[1], 0, 0, 0); \
            acc[2] = __builtin_amdgcn_mfma_f32_16x16x32_f16(af, Wc, acc[2], 0, 0, 0); \
            acc[3] = __builtin_amdgcn_mfma_f32_16x16x32_f16(af, Wd, acc[3], 0, 0, 0); \
            __builtin_amdgcn_s_setprio(0);                                     \
        }

        auto gather_pass = [&](int half) {
            const unsigned short* cbaseh = inT + q * 8 + half * 32;
            uint4 Ca0, Cb0, Cc0, Cd0, Ca1, Cb1, Cc1, Cd1;
            f16x4 wv0, wv1;
            f16x8 Ba0, Bb0, Bc0, Bd0, Ba1, Bb1, Bc1, Bd1;
            // load tap kt into the given register set (unconditional)
            auto loadTap = [&](int kt, uint4& Ca, uint4& Cb, uint4& Cc, uint4& Cd,
                               f16x4& wv, f16x8& Ba, f16x8& Bb, f16x8& Bc, f16x8& Bd) {
                uint2 aa = sA[kt * 64 + pxl];
                wv = sWp[kt * 64 + pxl];
                unsigned p00 = aa.x & 0xFFFu, p01 = (aa.x >> 16) & 0xFFFu;
                unsigned p10 = aa.y & 0xFFFu, p11 = aa.y >> 16;
                unsigned a00 = (unsigned)(((int)(p00 << 6)) + qb) ^ ((p00 & 7u) << 4);
                unsigned a01 = (unsigned)(((int)(p01 << 6)) + qb) ^ ((p01 & 7u) << 4);
                unsigned a10 = (unsigned)(((int)(p10 << 6)) + qb) ^ ((p10 & 7u) << 4);
                unsigned a11 = (unsigned)(((int)(p11 << 6)) + qb) ^ ((p11 & 7u) << 4);
                Ca = *(const uint4*)(arena + a00);
                Cb = *(const uint4*)(arena + a01);
                Cc = *(const uint4*)(arena + a10);
                Cd = *(const uint4*)(arena + a11);
                if (aa.x & 0x80000000u) {  // rare: window miss -> global path
                    Ca = *(const uint4*)(cbaseh + (p00 << 6));
                    Cb = *(const uint4*)(cbaseh + (p01 << 6));
                    Cc = *(const uint4*)(cbaseh + (p10 << 6));
                    Cd = *(const uint4*)(cbaseh + (p11 << 6));
                }
                Ba = loadB_mn(kt * 2 + half, 0);
                Bb = loadB_mn(kt * 2 + half, 1);
                Bc = loadB_mn(kt * 2 + half, 2);
                Bd = loadB_mn(kt * 2 + half, 3);
            };
            loadTap(0, Ca0, Cb0, Cc0, Cd0, wv0, Ba0, Bb0, Bc0, Bd0);
#pragma unroll 1
            for (int kt = 0; kt < 4; ++kt) {
                loadTap(2 * kt + 1, Ca1, Cb1, Cc1, Cd1, wv1, Ba1, Bb1, Bc1, Bd1);
                PROC(Ca0, Cb0, Cc0, Cd0, wv0, Ba0, Bb0, Bc0, Bd0)
                loadTap(2 * kt + 2, Ca0, Cb0, Cc0, Cd0, wv0, Ba0, Bb0, Bc0, Bd0);
                PROC(Ca1, Cb1, Cc1, Cd1, wv1, Ba1, Bb1, Bc1, Bd1)
            }
            PROC(Ca0, Cb0, Cc0, Cd0, wv0, Ba0, Bb0, Bc0, Bd0)   // tap 8
        };

        gather_pass(1);            // window currently holds half-1
        __syncthreads();           // all waves done reading half-1 window
        stage_half(0);
        __syncthreads();
        gather_pass(0);
#undef PROC
    }

    // epilogue: direct D-scrambled coalesced store; K3 decodes.
    float* gp = p.ws + WS_GATES + ((size_t)((gate * 8 + b) * 64 + row) << 12);
#pragma unroll
    for (int ot = 0; ot < 4; ++ot)
        *(float4*)(gp + ((w * 4 + ot) * 64 + l) * 4) = *(float4*)&acc[ot];
}

// ---------------------------------------------------------------------------
// K3: pointwise ConvLSTM combine, reading D-scrambled gates (coalesced) and
//   decoding (o,px) for c/out access (16B-segment granularity).
//   grid: 8192 blocks of 256.
// ---------------------------------------------------------------------------
__global__ __launch_bounds__(256) void k3_lstm(Params p) {
    int T = blockIdx.x * 256 + threadIdx.x;        // [b][row][i] over scrambled
    int i = T & 4095; int row = (T >> 12) & 63; int b = T >> 18;
    const float* gp = p.ws + WS_GATES;
    size_t base = ((size_t)(b * 64 + row) << 12) + i;
    float gi = gp[base];
    float gf = gp[base + 1 * PLANE];
    float gc = gp[base + 2 * PLANE];
    float go = gp[base + 3 * PLANE];
    // decode scramble: i = ((w*4+ot)*64 + l)*4 + r
    int r = i & 3; int l = (i >> 2) & 63; int u = i >> 8;
    int w = u >> 2; int ot = u & 3;
    int o = ot * 16 + (l & 15);
    int px = w * 16 + (l >> 4) * 4 + r;
    size_t cidx = ((size_t)(b * 64 + o) << 12) + row * 64 + px;
    float cold = p.c[cidx];
    float ig = sigf(gi + cold * p.wci[o] + p.bi[o]);
    float fg = sigf(gf + cold * p.wcf[o] + p.bf[o]);
    float cn = fg * cold + ig * tanhfast(gc + p.bc[o]);
    float og = sigf(go + cn * p.wco[o] + p.bo[o]);
    p.out[cidx] = og * tanhfast(cn);
    p.out[cidx + PLANE] = cn;
}

// ---------------------------------------------------------------------------
extern "C" void kernel_launch(void* const* d_in, const int* in_sizes, int n_in,
                              void* d_out, int out_size, void* d_ws, size_t ws_size,
                              hipStream_t stream) {
    (void)in_sizes; (void)n_in; (void)out_size; (void)ws_size;
    Params P;
    P.x = (const float*)d_in[0];
    P.h = (const float*)d_in[1];
    P.c = (const float*)d_in[2];
    for (int i = 0; i < 8; ++i) {
        P.w[i]  = (const float*)d_in[3 + 3 * i];
        P.ow[i] = (const float*)d_in[4 + 3 * i];
        P.ob[i] = (const float*)d_in[5 + 3 * i];
    }
    P.bi  = (const float*)d_in[27];
    P.bf  = (const float*)d_in[28];
    P.bc  = (const float*)d_in[29];
    P.bo  = (const float*)d_in[30];
    P.wci = (const float*)d_in[31];
    P.wcf = (const float*)d_in[32];
    P.wco = (const float*)d_in[33];
    P.out = (float*)d_out;
    P.ws  = (float*)d_ws;

    k0_prep   <<<dim3(2753), dim3(256), 0, stream>>>(P);
    k2_fused  <<<dim3(2048), dim3(256), 0, stream>>>(P);
    k3_lstm   <<<dim3(8192), dim3(256), 0, stream>>>(P);
}

// Round 14
// 230.711 us; speedup vs baseline: 1.6509x; 1.0088x over previous
//
#include <hip/hip_runtime.h>
#include <math.h>

// Problem constants (B=8, Cin=Cout=64, H=W=64, 3x3 kernel pad 1)
#define NB     8
#define NC     64
#define HW     4096           // 64*64
#define PLANE  2097152        // NB*NC*HW

// Workspace layout (float-slot offsets)
#define WS_WB     0           // f16 wB[8][72][64][8]   (294912 h = 147456 f)
#define WS_OWB    147456      // f16 owB[8][72][32][8]  (147456 h = 73728 f)
#define WS_OB     221184      // f32 obAll[8][27]
#define WS_GATES  221400      // f32 gates[4][8][64][64][64] NATURAL layout (R14)
#define WS_XT     8610008     // f16 xT[8][4096][64] HWC  (1048576 f)
#define WS_HT     9658584     // f16 hT[8][4096][64] HWC  (1048576 f)
// total = 10707160 floats = 42.8 MB

typedef _Float16 f16x8 __attribute__((ext_vector_type(8)));
typedef _Float16 f16x4 __attribute__((ext_vector_type(4)));
typedef _Float16 f16x2 __attribute__((ext_vector_type(2)));
typedef float    f32x4 __attribute__((ext_vector_type(4)));

struct Params {
    const float* x; const float* h; const float* c;
    const float* w[8]; const float* ow[8]; const float* ob[8];
    const float* bi; const float* bf; const float* bc; const float* bo;
    const float* wci; const float* wcf; const float* wco;
    float* out; float* ws;
};

__device__ __forceinline__ float sigf(float v) { return 1.f / (1.f + __expf(-v)); }
__device__ __forceinline__ float tanhfast(float v) {
    return 1.f - 2.f / (__expf(2.f * v) + 1.f);
}
__device__ __forceinline__ unsigned short f2h(float v) {
    _Float16 h = (_Float16)v;
    return __builtin_bit_cast(unsigned short, h);
}
__device__ __forceinline__ f16x2 bch(unsigned d) { return __builtin_bit_cast(f16x2, d); }

// ---------------------------------------------------------------------------
// K0 (merged): weight B-frag packing + biases (blocks 0..1728), and
//   CHW fp32 -> HWC f16 transpose of x/h (blocks 1729..2752).
// ---------------------------------------------------------------------------
__global__ __launch_bounds__(256) void k0_prep(Params p) {
    if (blockIdx.x < 1729) {
        int i = blockIdx.x * 256 + threadIdx.x;
        unsigned short* wb  = (unsigned short*)(p.ws + WS_WB);
        unsigned short* owb = (unsigned short*)(p.ws + WS_OWB);
        if (i < 294912) {
            int br = i / 36864; int r = i % 36864;
            int kgrp = r >> 9; int o = (r >> 3) & 63; int j = r & 7;
            int k = kgrp * 8 + j;
            int ktap = k >> 6; int c = k & 63;
            wb[i] = f2h(p.w[br][(o * 64 + c) * 9 + ktap]);
        } else if (i < 294912 + 147456) {
            int ii = i - 294912;
            int br = ii / 18432; int r = ii % 18432;
            int kgrp = r >> 8; int o = (r >> 3) & 31; int j = r & 7;
            int k = kgrp * 8 + j;
            int ktap = k >> 6; int c = k & 63;
            float v = (o < 27) ? p.ow[br][(o * 64 + c) * 9 + ktap] : 0.f;
            owb[ii] = f2h(v);
        } else if (i < 294912 + 147456 + 216) {
            int ii = i - 442368;
            int br = ii / 27; int j = ii % 27;
            p.ws[WS_OB + ii] = p.ob[br][j];
        }
        return;
    }
    __shared__ float tile[64][65];
    int bid = blockIdx.x - 1729;
    int row = bid & 63; int b = (bid >> 6) & 7; int ten = bid >> 9;
    const float* src = ten ? p.h : p.x;
    unsigned short* dst = (unsigned short*)(p.ws + (ten ? WS_HT : WS_XT));
    int t = threadIdx.x; int lane = t & 63; int w4 = t >> 6;
#pragma unroll
    for (int i = 0; i < 16; ++i) {
        int c = i * 4 + w4;
        tile[c][lane] = src[((size_t)(b * 64 + c) << 12) + row * 64 + lane];
    }
    __syncthreads();
#pragma unroll
    for (int i = 0; i < 16; ++i) {
        int px = i * 4 + w4;
        dst[((size_t)(b * 4096 + row * 64 + px) << 6) + lane] = f2h(tile[lane][px]);
    }
}

// ---------------------------------------------------------------------------
// K2 v21 (= v20 + LDS-descramble epilogue -> natural gate layout).
//   R13 post-mortem: ping-pong unroll -23% (k2 98us). Remaining e2e gap
//   (~134us, constant all session) — largest addressable piece is K3's
//   scatter: its decode changes channel o every 4 threads, so c/out
//   accesses touch 16 distant planes per wave (16B used per 64B line,
//   ~4x over-fetch on ~25MB). THIS ROUND: descramble in K2's epilogue —
//   the 36KB arena is dead after the last gather; drop acc into a
//   stride-66 [o][px] f32 tile (2-way bank alias = free), barrier, stream
//   out in NATURAL [gate][b][o][row][px] layout (256B coalesced runs).
//   K3 becomes fully linear (gates/c/out all coalesced).
//   Hot loops byte-identical to v20 (epilogue-only change, no new
//   persistent register state).
// ---------------------------------------------------------------------------
__global__ __launch_bounds__(256, 3) void k2_fused(Params p) {
    __shared__ __align__(16) unsigned char arena[36864];
    // win:   [0, 20480)      f16 [5][64px][32ch], byte=((r*64+px)<<6)+seg*16 ^ ((px&7)<<4)
    // sA:    [20480, 25088)  uint2 [9][64]  packed clamped pix (+far bit31 in .x)
    // sWp:   [25088, 29696)  f16x4 [9][64]  folded bilinear weights
    // sOff:  [29696, 36824)  f32 [27][66]
    // sG (epilogue only, aliases everything): f32 [64][66] descramble tile
    uint2* sA   = (uint2*)(arena + 20480);
    f16x4* sWp  = (f16x4*)(arena + 25088);
    float* sOff = (float*)(arena + 29696);

    int bid = blockIdx.x;
    // XCD-aware decode: same-b blocks share an XCD's L2.
    int b = bid & 7; int gate = (bid >> 3) & 3; int row = bid >> 5;
    int t = threadIdx.x; int l = t & 63; int w = t >> 6;
    int q = l >> 4; int n = l & 15;
    int pxl = w * 16 + n;

    const unsigned short* wBp = (const unsigned short*)(p.ws + WS_WB);
    const unsigned short* owb = (const unsigned short*)(p.ws + WS_OWB);

    // per-lane gather address bias: byte = (pix<<6) + qb, then ^ ((pix&7)<<4)
    int qb = q * 16 - (row - 2) * 4096;

    f32x4 acc[4];
#pragma unroll
    for (int ot = 0; ot < 4; ++ot) acc[ot] = (f32x4){0.f, 0.f, 0.f, 0.f};

    for (int sub = 0; sub < 2; ++sub) {
        int br = gate * 2 + sub;
        const unsigned short* inT =
            (const unsigned short*)(p.ws + (sub ? WS_HT : WS_XT)) + ((size_t)b << 18);
        const float* obp = p.ws + WS_OB + br * 27;

        // ---- stage one 32-ch half of the 5-row window (zero-filled OOB) ----
        auto stage_half = [&](int half) {
#pragma unroll
            for (int it = 0; it < 5; ++it) {
                int u = t + it * 256;                  // u in [0,1280)
                int r = u >> 8; int px = (u >> 2) & 63; int seg = u & 3;
                int grow = row - 2 + r;
                uint4 v = {0u, 0u, 0u, 0u};
                if ((unsigned)grow < 64u)
                    v = *(const uint4*)(inT + (((size_t)grow * 64 + px) << 6) + half * 32 + seg * 8);
                unsigned byte = ((unsigned)u << 4) ^ (((unsigned)px & 7u) << 4);
                *(uint4*)(arena + byte) = v;
            }
        };

        // ---- offset-conv helpers: slice sl in [0,9): dy=sl/3, dxk=sl%3 ----
        auto loadA_oc = [&](int sl) -> f16x8 {
            int dy = sl / 3; int dxk = sl % 3;
            int spx = pxl + dxk - 1;                  // [-1, 64]
            int spc = min(max(spx, 0), 63);
            unsigned byte = ((unsigned)((((dy + 1) * 64 + spc) << 6) + q * 16))
                            ^ (((unsigned)spc & 7u) << 4);
            f16x8 af = *(const f16x8*)(arena + byte);
            if ((unsigned)spx >= 64u) {               // zero halo columns
#pragma unroll
                for (int z = 0; z < 8; ++z) af[z] = (_Float16)0.f;
            }
            return af;
        };
        auto loadB_oc = [&](int sl, int half, int ot) -> f16x8 {
            int dy = sl / 3; int dxk = sl % 3; int s = dxk * 2 + half;
            int kb = (br * 72 + dy * 24 + s * 4 + q) * 32;
            return *(const f16x8*)(owb + (size_t)(kb + ot * 16 + n) * 8);
        };
        // ping-pong unroll-2 over 9 K-slices: no rotation copies, no branch.
        auto offconv_pass = [&](int half, f32x4& cA, f32x4& cB) {
            f16x8 a0 = loadA_oc(0), b0 = loadB_oc(0, half, 0), b1 = loadB_oc(0, half, 1);
            f16x8 a1, b2, b3;
#pragma unroll 1
            for (int s2 = 0; s2 < 4; ++s2) {
                a1 = loadA_oc(2 * s2 + 1);
                b2 = loadB_oc(2 * s2 + 1, half, 0);
                b3 = loadB_oc(2 * s2 + 1, half, 1);
                __builtin_amdgcn_s_setprio(1);
                cA = __builtin_amdgcn_mfma_f32_16x16x32_f16(a0, b0, cA, 0, 0, 0);
                cB = __builtin_amdgcn_mfma_f32_16x16x32_f16(a0, b1, cB, 0, 0, 0);
                __builtin_amdgcn_s_setprio(0);
                a0 = loadA_oc(2 * s2 + 2);
                b0 = loadB_oc(2 * s2 + 2, half, 0);
                b1 = loadB_oc(2 * s2 + 2, half, 1);
                __builtin_amdgcn_s_setprio(1);
                cA = __builtin_amdgcn_mfma_f32_16x16x32_f16(a1, b2, cA, 0, 0, 0);
                cB = __builtin_amdgcn_mfma_f32_16x16x32_f16(a1, b3, cB, 0, 0, 0);
                __builtin_amdgcn_s_setprio(0);
            }
            __builtin_amdgcn_s_setprio(1);
            cA = __builtin_amdgcn_mfma_f32_16x16x32_f16(a0, b0, cA, 0, 0, 0);
            cB = __builtin_amdgcn_mfma_f32_16x16x32_f16(a0, b1, cB, 0, 0, 0);
            __builtin_amdgcn_s_setprio(0);
        };

        f32x4 c0 = (f32x4){0.f,0.f,0.f,0.f}, c1 = (f32x4){0.f,0.f,0.f,0.f};
        f32x4 c2 = (f32x4){0.f,0.f,0.f,0.f}, c3 = (f32x4){0.f,0.f,0.f,0.f};

        __syncthreads();           // window/sA/sWp free (prev sub done)
        stage_half(0);
        __syncthreads();
        offconv_pass(0, c0, c1);   // s even K-slices (ch 0..31)
        __syncthreads();           // all waves done reading half-0 window
        stage_half(1);
        __syncthreads();
        offconv_pass(1, c2, c3);   // s odd K-slices (ch 32..63)

        f32x4 acc2[2];
        acc2[0] = c0 + c2;
        acc2[1] = c1 + c3;

        // D-frags (+bias) -> sOff[j][px]; j=ot*16+n, px=w*16+q*4+r; j<27 only
#pragma unroll
        for (int ot = 0; ot < 2; ++ot) {
            int j = ot * 16 + n;
            if (j < 27) {
                float bias = obp[j];
#pragma unroll
                for (int r = 0; r < 4; ++r)
                    sOff[j * 66 + w * 16 + q * 4 + r] = acc2[ot][r] + bias;
            }
        }
        __syncthreads();   // sOff visible

        // ---- Phase A: bilinear coords + (mask*inbound)-folded weights ----
        for (int i2 = t; i2 < 576; i2 += 256) {
            int px = i2 & 63; int k = i2 >> 6;
            float dy = sOff[(2 * k) * 66 + px];
            float dx = sOff[(2 * k + 1) * 66 + px];
            float mm = sOff[(18 + k) * 66 + px];
            float m = sigf(mm);
            int ki = k / 3, kj = k % 3;
            float py  = (float)(row + ki - 1) + dy;
            float pxx = (float)(px + kj - 1) + dx;
            float y0f = floorf(py), x0f = floorf(pxx);
            float wy = py - y0f, wx = pxx - x0f;
            int y0 = (int)y0f, x0 = (int)x0f;
            float y0i = ((unsigned)y0 < 64u) ? 1.f : 0.f;
            float y1i = ((unsigned)(y0 + 1) < 64u) ? 1.f : 0.f;
            float x0i = ((unsigned)x0 < 64u) ? 1.f : 0.f;
            float x1i = ((unsigned)(x0 + 1) < 64u) ? 1.f : 0.f;
            float w00 = (1.f - wy) * (1.f - wx) * m * y0i * x0i;
            float w01 = (1.f - wy) * wx         * m * y0i * x1i;
            float w10 = wy         * (1.f - wx) * m * y1i * x0i;
            float w11 = wy         * wx         * m * y1i * x1i;
            int cy0 = min(max(y0, 0), 63),     cy1 = min(max(y0 + 1, 0), 63);
            int cx0 = min(max(x0, 0), 63),     cx1 = min(max(x0 + 1, 0), 63);
            // far: clamped corner row outside staged window [row-2, row+2]
            int s0 = cy0 - (row - 2); int s1 = cy1 - (row - 2);
            unsigned farb = (((unsigned)s0 > 4u) || ((unsigned)s1 > 4u)) ? 0x80000000u : 0u;
            sA[k * 64 + px] = make_uint2(((unsigned)(cy0 * 64 + cx0) | ((unsigned)(cy0 * 64 + cx1) << 16)) | farb,
                                         (unsigned)(cy1 * 64 + cx0) | ((unsigned)(cy1 * 64 + cx1) << 16));
            sWp[k * 64 + px] = (f16x4){(_Float16)w00, (_Float16)w01, (_Float16)w10, (_Float16)w11};
        }
        __syncthreads();

        // ---- per-half pipelined LDS gather + B-frag register pipeline ----
        auto loadB_mn = [&](int S, int ot) -> f16x8 {
            int kb = (br * 72 + S * 4 + q) * 64;
            return *(const f16x8*)(wBp + (size_t)(kb + ot * 16 + n) * 8);
        };

        // Packed-f16 blend: per corner-dword one v_pk_fma_f16; af is
        // already packed f16 (no unpack, no repack).
#define PROC(Ca, Cb, Cc, Cd, WV, Wa, Wb, Wc, Wd)                               \
        {                                                                      \
            f16x2 pw0 = (f16x2){WV[0], WV[0]};                                 \
            f16x2 pw1 = (f16x2){WV[1], WV[1]};                                 \
            f16x2 pw2 = (f16x2){WV[2], WV[2]};                                 \
            f16x2 pw3 = (f16x2){WV[3], WV[3]};                                 \
            f16x2 a0 = bch(Ca.x) * pw0 + bch(Cb.x) * pw1                       \
                     + bch(Cc.x) * pw2 + bch(Cd.x) * pw3;                      \
            f16x2 a1 = bch(Ca.y) * pw0 + bch(Cb.y) * pw1                       \
                     + bch(Cc.y) * pw2 + bch(Cd.y) * pw3;                      \
            f16x2 a2 = bch(Ca.z) * pw0 + bch(Cb.z) * pw1                       \
                     + bch(Cc.z) * pw2 + bch(Cd.z) * pw3;                      \
            f16x2 a3 = bch(Ca.w) * pw0 + bch(Cb.w) * pw1                       \
                     + bch(Cc.w) * pw2 + bch(Cd.w) * pw3;                      \
            f16x8 af = (f16x8){a0[0], a0[1], a1[0], a1[1],                     \
                               a2[0], a2[1], a3[0], a3[1]};                    \
            __builtin_amdgcn_s_setprio(1);                                     \
            acc[0] = __builtin_amdgcn_mfma_f32_16x16x32_f16(af, Wa, acc[0], 0, 0, 0); \
            acc[1] = __builtin_amdgcn_mfma_f32_16x16x32_f16(af, Wb, acc[1], 0, 0, 0); \
            acc[2] = __builtin_amdgcn_mfma_f32_16x16x32_f16(af, Wc, acc[2], 0, 0, 0); \
            acc[3] = __builtin_amdgcn_mfma_f32_16x16x32_f16(af, Wd, acc[3], 0, 0, 0); \
            __builtin_amdgcn_s_setprio(0);                                     \
        }

        auto gather_pass = [&](int half) {
            const unsigned short* cbaseh = inT + q * 8 + half * 32;
            uint4 Ca0, Cb0, Cc0, Cd0, Ca1, Cb1, Cc1, Cd1;
            f16x4 wv0, wv1;
            f16x8 Ba0, Bb0, Bc0, Bd0, Ba1, Bb1, Bc1, Bd1;
            // load tap kt into the given register set (unconditional)
            auto loadTap = [&](int kt, uint4& Ca, uint4& Cb, uint4& Cc, uint4& Cd,
                               f16x4& wv, f16x8& Ba, f16x8& Bb, f16x8& Bc, f16x8& Bd) {
                uint2 aa = sA[kt * 64 + pxl];
                wv = sWp[kt * 64 + pxl];
                unsigned p00 = aa.x & 0xFFFu, p01 = (aa.x >> 16) & 0xFFFu;
                unsigned p10 = aa.y & 0xFFFu, p11 = aa.y >> 16;
                unsigned a00 = (unsigned)(((int)(p00 << 6)) + qb) ^ ((p00 & 7u) << 4);
                unsigned a01 = (unsigned)(((int)(p01 << 6)) + qb) ^ ((p01 & 7u) << 4);
                unsigned a10 = (unsigned)(((int)(p10 << 6)) + qb) ^ ((p10 & 7u) << 4);
                unsigned a11 = (unsigned)(((int)(p11 << 6)) + qb) ^ ((p11 & 7u) << 4);
                Ca = *(const uint4*)(arena + a00);
                Cb = *(const uint4*)(arena + a01);
                Cc = *(const uint4*)(arena + a10);
                Cd = *(const uint4*)(arena + a11);
                if (aa.x & 0x80000000u) {  // rare: window miss -> global path
                    Ca = *(const uint4*)(cbaseh + (p00 << 6));
                    Cb = *(const uint4*)(cbaseh + (p01 << 6));
                    Cc = *(const uint4*)(cbaseh + (p10 << 6));
                    Cd = *(const uint4*)(cbaseh + (p11 << 6));
                }
                Ba = loadB_mn(kt * 2 + half, 0);
                Bb = loadB_mn(kt * 2 + half, 1);
                Bc = loadB_mn(kt * 2 + half, 2);
                Bd = loadB_mn(kt * 2 + half, 3);
            };
            loadTap(0, Ca0, Cb0, Cc0, Cd0, wv0, Ba0, Bb0, Bc0, Bd0);
#pragma unroll 1
            for (int kt = 0; kt < 4; ++kt) {
                loadTap(2 * kt + 1, Ca1, Cb1, Cc1, Cd1, wv1, Ba1, Bb1, Bc1, Bd1);
                PROC(Ca0, Cb0, Cc0, Cd0, wv0, Ba0, Bb0, Bc0, Bd0)
                loadTap(2 * kt + 2, Ca0, Cb0, Cc0, Cd0, wv0, Ba0, Bb0, Bc0, Bd0);
                PROC(Ca1, Cb1, Cc1, Cd1, wv1, Ba1, Bb1, Bc1, Bd1)
            }
            PROC(Ca0, Cb0, Cc0, Cd0, wv0, Ba0, Bb0, Bc0, Bd0)   // tap 8
        };

        gather_pass(1);            // window currently holds half-1
        __syncthreads();           // all waves done reading half-1 window
        stage_half(0);
        __syncthreads();
        gather_pass(0);
#undef PROC
    }

    // ---- epilogue: descramble via LDS -> natural [gate][b][o][row][px] ----
    __syncthreads();               // arena fully dead (all gathers done)
    float* sG = (float*)arena;     // [64 o][66] stride-66 f32, 16896 B
#pragma unroll
    for (int ot = 0; ot < 4; ++ot) {
        int o = ot * 16 + n;
#pragma unroll
        for (int r = 0; r < 4; ++r)
            sG[o * 66 + (w * 16 + q * 4 + r)] = acc[ot][r];
    }
    __syncthreads();
    float* gp = p.ws + WS_GATES + (size_t)gate * PLANE
              + (((size_t)b * 64) << 12) + row * 64;
#pragma unroll
    for (int ii = 0; ii < 16; ++ii) {
        int i = t + ii * 256;
        int o = i >> 6; int px = i & 63;
        gp[((size_t)o << 12) + px] = sG[o * 66 + px];
    }
}

// ---------------------------------------------------------------------------
// K3: pointwise ConvLSTM combine — fully linear now (gates in natural
//   [gate][b][o][row][px] layout matches c/out CHW exactly). All six
//   streams coalesced. grid: 8192 blocks of 256.
// ---------------------------------------------------------------------------
__global__ __launch_bounds__(256) void k3_lstm(Params p) {
    size_t T = (size_t)blockIdx.x * 256 + threadIdx.x;   // linear over [b][o][row][px]
    const float* gp = p.ws + WS_GATES;
    float gi = gp[T];
    float gf = gp[T + 1 * (size_t)PLANE];
    float gc = gp[T + 2 * (size_t)PLANE];
    float go = gp[T + 3 * (size_t)PLANE];
    int o = ((int)(T >> 12)) & 63;
    float cold = p.c[T];
    float ig = sigf(gi + cold * p.wci[o] + p.bi[o]);
    float fg = sigf(gf + cold * p.wcf[o] + p.bf[o]);
    float cn = fg * cold + ig * tanhfast(gc + p.bc[o]);
    float og = sigf(go + cn * p.wco[o] + p.bo[o]);
    p.out[T] = og * tanhfast(cn);
    p.out[T + (size_t)PLANE] = cn;
}

// ---------------------------------------------------------------------------
extern "C" void kernel_launch(void* const* d_in, const int* in_sizes, int n_in,
                              void* d_out, int out_size, void* d_ws, size_t ws_size,
                              hipStream_t stream) {
    (void)in_sizes; (void)n_in; (void)out_size; (void)ws_size;
    Params P;
    P.x = (const float*)d_in[0];
    P.h = (const float*)d_in[1];
    P.c = (const float*)d_in[2];
    for (int i = 0; i < 8; ++i) {
        P.w[i]  = (const float*)d_in[3 + 3 * i];
        P.ow[i] = (const float*)d_in[4 + 3 * i];
        P.ob[i] = (const float*)d_in[5 + 3 * i];
    }
    P.bi  = (const float*)d_in[27];
    P.bf  = (const float*)d_in[28];
    P.bc  = (const float*)d_in[29];
    P.bo  = (const float*)d_in[30];
    P.wci = (const float*)d_in[31];
    P.wcf = (const float*)d_in[32];
    P.wco = (const float*)d_in[33];
    P.out = (float*)d_out;
    P.ws  = (float*)d_ws;

    k0_prep   <<<dim3(2753), dim3(256), 0, stream>>>(P);
    k2_fused  <<<dim3(2048), dim3(256), 0, stream>>>(P);
    k3_lstm   <<<dim3(8192), dim3(256), 0, stream>>>(P);
}

// Round 16
// 228.851 us; speedup vs baseline: 1.6643x; 1.0081x over previous
//
#include <hip/hip_runtime.h>
#include <math.h>

// Problem constants (B=8, Cin=Cout=64, H=W=64, 3x3 kernel pad 1)
#define NB     8
#define NC     64
#define HW     4096           // 64*64
#define PLANE  2097152        // NB*NC*HW

// Workspace layout (float-slot offsets)
#define WS_WB     0           // f16 wB[8][72][64][8]   (294912 h = 147456 f)
#define WS_OWB    147456      // f16 owB[8][72][32][8]  (147456 h = 73728 f)
#define WS_OB     221184      // f32 obAll[8][27]
#define WS_GATES  221400      // f32 gates[4][8][64][64][64] NATURAL layout (R14)
#define WS_XT     8610008     // f16 xT[8][4096][64] HWC  (1048576 f)
#define WS_HT     9658584     // f16 hT[8][4096][64] HWC  (1048576 f)
// total = 10707160 floats = 42.8 MB

typedef _Float16 f16x8 __attribute__((ext_vector_type(8)));
typedef _Float16 f16x4 __attribute__((ext_vector_type(4)));
typedef _Float16 f16x2 __attribute__((ext_vector_type(2)));
typedef float    f32x4 __attribute__((ext_vector_type(4)));

struct Params {
    const float* x; const float* h; const float* c;
    const float* w[8]; const float* ow[8]; const float* ob[8];
    const float* bi; const float* bf; const float* bc; const float* bo;
    const float* wci; const float* wcf; const float* wco;
    float* out; float* ws;
};

__device__ __forceinline__ float sigf(float v) { return 1.f / (1.f + __expf(-v)); }
__device__ __forceinline__ float tanhfast(float v) {
    return 1.f - 2.f / (__expf(2.f * v) + 1.f);
}
__device__ __forceinline__ unsigned short f2h(float v) {
    _Float16 h = (_Float16)v;
    return __builtin_bit_cast(unsigned short, h);
}
__device__ __forceinline__ f16x2 bch(unsigned d) { return __builtin_bit_cast(f16x2, d); }

// ---------------------------------------------------------------------------
// K0 (merged): weight B-frag packing + biases (blocks 0..1728), and
//   CHW fp32 -> HWC f16 transpose of x/h (blocks 1729..2752).
// ---------------------------------------------------------------------------
__global__ __launch_bounds__(256) void k0_prep(Params p) {
    if (blockIdx.x < 1729) {
        int i = blockIdx.x * 256 + threadIdx.x;
        unsigned short* wb  = (unsigned short*)(p.ws + WS_WB);
        unsigned short* owb = (unsigned short*)(p.ws + WS_OWB);
        if (i < 294912) {
            int br = i / 36864; int r = i % 36864;
            int kgrp = r >> 9; int o = (r >> 3) & 63; int j = r & 7;
            int k = kgrp * 8 + j;
            int ktap = k >> 6; int c = k & 63;
            wb[i] = f2h(p.w[br][(o * 64 + c) * 9 + ktap]);
        } else if (i < 294912 + 147456) {
            int ii = i - 294912;
            int br = ii / 18432; int r = ii % 18432;
            int kgrp = r >> 8; int o = (r >> 3) & 31; int j = r & 7;
            int k = kgrp * 8 + j;
            int ktap = k >> 6; int c = k & 63;
            float v = (o < 27) ? p.ow[br][(o * 64 + c) * 9 + ktap] : 0.f;
            owb[ii] = f2h(v);
        } else if (i < 294912 + 147456 + 216) {
            int ii = i - 442368;
            int br = ii / 27; int j = ii % 27;
            p.ws[WS_OB + ii] = p.ob[br][j];
        }
        return;
    }
    __shared__ float tile[64][65];
    int bid = blockIdx.x - 1729;
    int row = bid & 63; int b = (bid >> 6) & 7; int ten = bid >> 9;
    const float* src = ten ? p.h : p.x;
    unsigned short* dst = (unsigned short*)(p.ws + (ten ? WS_HT : WS_XT));
    int t = threadIdx.x; int lane = t & 63; int w4 = t >> 6;
#pragma unroll
    for (int i = 0; i < 16; ++i) {
        int c = i * 4 + w4;
        tile[c][lane] = src[((size_t)(b * 64 + c) << 12) + row * 64 + lane];
    }
    __syncthreads();
#pragma unroll
    for (int i = 0; i < 16; ++i) {
        int px = i * 4 + w4;
        dst[((size_t)(b * 4096 + row * 64 + px) << 6) + lane] = f2h(tile[lane][px]);
    }
}

// ---------------------------------------------------------------------------
// K2 v23 (= v22 with the XOR-decode fix): precomputed swizzled LDS addrs.
//   R15 post-mortem: v22 FAILED (absmax 0.68) — encode/decode carry bug.
//   Old addr = (base + q16) ^ sw (base=wpix<<6 bits4-5 clear, sw bits4-6,
//   q16 bits4-5). v22 stored h = base ^ sw and decoded h + q16: the ADD
//   carries into bit6+ whenever sw[4:5] + q16 >= 64 -> wrong pixel block.
//   FIX (algebraic): base + q16 = base ^ q16 (disjoint bits), so correct
//   addr = h ^ q16. Decode uses XOR instead of ADD — same 2 ops/corner,
//   bit-exact with v21. Bit15 far flag untouched (h<=0x5030, q16<=48).
//   Carried: v20 ping-pong pipelines, packed-f16 blend, half-channel
//   window, 36864B arena, 3 blocks/CU, XOR bank swizzle, B-frag reg
//   pipeline, XCD swizzle b=bid&7, natural-layout descramble epilogue.
// ---------------------------------------------------------------------------
__global__ __launch_bounds__(256, 3) void k2_fused(Params p) {
    __shared__ __align__(16) unsigned char arena[36864];
    // win:   [0, 20480)      f16 [5][64px][32ch], byte=((r*64+px)<<6)+seg*16 ^ ((px&7)<<4)
    // sA:    [20480, 25088)  uint2 [9][64]  4x16-bit pre-swizzled corner addrs
    //                        (bit15 = far flag; far stores global pix)
    // sWp:   [25088, 29696)  f16x4 [9][64]  folded bilinear weights
    // sOff:  [29696, 36824)  f32 [27][66]
    // sG (epilogue only, aliases everything): f32 [64][66] descramble tile
    uint2* sA   = (uint2*)(arena + 20480);
    f16x4* sWp  = (f16x4*)(arena + 25088);
    float* sOff = (float*)(arena + 29696);

    int bid = blockIdx.x;
    // XCD-aware decode: same-b blocks share an XCD's L2.
    int b = bid & 7; int gate = (bid >> 3) & 3; int row = bid >> 5;
    int t = threadIdx.x; int l = t & 63; int w = t >> 6;
    int q = l >> 4; int n = l & 15;
    int pxl = w * 16 + n;

    const unsigned short* wBp = (const unsigned short*)(p.ws + WS_WB);
    const unsigned short* owb = (const unsigned short*)(p.ws + WS_OWB);

    unsigned q16 = (unsigned)(q * 16);   // per-lane channel-segment offset

    f32x4 acc[4];
#pragma unroll
    for (int ot = 0; ot < 4; ++ot) acc[ot] = (f32x4){0.f, 0.f, 0.f, 0.f};

    for (int sub = 0; sub < 2; ++sub) {
        int br = gate * 2 + sub;
        const unsigned short* inT =
            (const unsigned short*)(p.ws + (sub ? WS_HT : WS_XT)) + ((size_t)b << 18);
        const float* obp = p.ws + WS_OB + br * 27;

        // ---- stage one 32-ch half of the 5-row window (zero-filled OOB) ----
        auto stage_half = [&](int half) {
#pragma unroll
            for (int it = 0; it < 5; ++it) {
                int u = t + it * 256;                  // u in [0,1280)
                int r = u >> 8; int px = (u >> 2) & 63; int seg = u & 3;
                int grow = row - 2 + r;
                uint4 v = {0u, 0u, 0u, 0u};
                if ((unsigned)grow < 64u)
                    v = *(const uint4*)(inT + (((size_t)grow * 64 + px) << 6) + half * 32 + seg * 8);
                unsigned byte = ((unsigned)u << 4) ^ (((unsigned)px & 7u) << 4);
                *(uint4*)(arena + byte) = v;
            }
        };

        // ---- offset-conv helpers: slice sl in [0,9): dy=sl/3, dxk=sl%3 ----
        auto loadA_oc = [&](int sl) -> f16x8 {
            int dy = sl / 3; int dxk = sl % 3;
            int spx = pxl + dxk - 1;                  // [-1, 64]
            int spc = min(max(spx, 0), 63);
            unsigned byte = ((unsigned)((((dy + 1) * 64 + spc) << 6) + q * 16))
                            ^ (((unsigned)spc & 7u) << 4);
            f16x8 af = *(const f16x8*)(arena + byte);
            if ((unsigned)spx >= 64u) {               // zero halo columns
#pragma unroll
                for (int z = 0; z < 8; ++z) af[z] = (_Float16)0.f;
            }
            return af;
        };
        auto loadB_oc = [&](int sl, int half, int ot) -> f16x8 {
            int dy = sl / 3; int dxk = sl % 3; int s = dxk * 2 + half;
            int kb = (br * 72 + dy * 24 + s * 4 + q) * 32;
            return *(const f16x8*)(owb + (size_t)(kb + ot * 16 + n) * 8);
        };
        // ping-pong unroll-2 over 9 K-slices: no rotation copies, no branch.
        auto offconv_pass = [&](int half, f32x4& cA, f32x4& cB) {
            f16x8 a0 = loadA_oc(0), b0 = loadB_oc(0, half, 0), b1 = loadB_oc(0, half, 1);
            f16x8 a1, b2, b3;
#pragma unroll 1
            for (int s2 = 0; s2 < 4; ++s2) {
                a1 = loadA_oc(2 * s2 + 1);
                b2 = loadB_oc(2 * s2 + 1, half, 0);
                b3 = loadB_oc(2 * s2 + 1, half, 1);
                __builtin_amdgcn_s_setprio(1);
                cA = __builtin_amdgcn_mfma_f32_16x16x32_f16(a0, b0, cA, 0, 0, 0);
                cB = __builtin_amdgcn_mfma_f32_16x16x32_f16(a0, b1, cB, 0, 0, 0);
                __builtin_amdgcn_s_setprio(0);
                a0 = loadA_oc(2 * s2 + 2);
                b0 = loadB_oc(2 * s2 + 2, half, 0);
                b1 = loadB_oc(2 * s2 + 2, half, 1);
                __builtin_amdgcn_s_setprio(1);
                cA = __builtin_amdgcn_mfma_f32_16x16x32_f16(a1, b2, cA, 0, 0, 0);
                cB = __builtin_amdgcn_mfma_f32_16x16x32_f16(a1, b3, cB, 0, 0, 0);
                __builtin_amdgcn_s_setprio(0);
            }
            __builtin_amdgcn_s_setprio(1);
            cA = __builtin_amdgcn_mfma_f32_16x16x32_f16(a0, b0, cA, 0, 0, 0);
            cB = __builtin_amdgcn_mfma_f32_16x16x32_f16(a0, b1, cB, 0, 0, 0);
            __builtin_amdgcn_s_setprio(0);
        };

        f32x4 c0 = (f32x4){0.f,0.f,0.f,0.f}, c1 = (f32x4){0.f,0.f,0.f,0.f};
        f32x4 c2 = (f32x4){0.f,0.f,0.f,0.f}, c3 = (f32x4){0.f,0.f,0.f,0.f};

        __syncthreads();           // window/sA/sWp free (prev sub done)
        stage_half(0);
        __syncthreads();
        offconv_pass(0, c0, c1);   // s even K-slices (ch 0..31)
        __syncthreads();           // all waves done reading half-0 window
        stage_half(1);
        __syncthreads();
        offconv_pass(1, c2, c3);   // s odd K-slices (ch 32..63)

        f32x4 acc2[2];
        acc2[0] = c0 + c2;
        acc2[1] = c1 + c3;

        // D-frags (+bias) -> sOff[j][px]; j=ot*16+n, px=w*16+q*4+r; j<27 only
#pragma unroll
        for (int ot = 0; ot < 2; ++ot) {
            int j = ot * 16 + n;
            if (j < 27) {
                float bias = obp[j];
#pragma unroll
                for (int r = 0; r < 4; ++r)
                    sOff[j * 66 + w * 16 + q * 4 + r] = acc2[ot][r] + bias;
            }
        }
        __syncthreads();   // sOff visible

        // ---- Phase A: bilinear coords + folded weights + PRE-SWIZZLED
        //      half-window corner addresses (bit15 = far flag) ----
        for (int i2 = t; i2 < 576; i2 += 256) {
            int px = i2 & 63; int k = i2 >> 6;
            float dy = sOff[(2 * k) * 66 + px];
            float dx = sOff[(2 * k + 1) * 66 + px];
            float mm = sOff[(18 + k) * 66 + px];
            float m = sigf(mm);
            int ki = k / 3, kj = k % 3;
            float py  = (float)(row + ki - 1) + dy;
            float pxx = (float)(px + kj - 1) + dx;
            float y0f = floorf(py), x0f = floorf(pxx);
            float wy = py - y0f, wx = pxx - x0f;
            int y0 = (int)y0f, x0 = (int)x0f;
            float y0i = ((unsigned)y0 < 64u) ? 1.f : 0.f;
            float y1i = ((unsigned)(y0 + 1) < 64u) ? 1.f : 0.f;
            float x0i = ((unsigned)x0 < 64u) ? 1.f : 0.f;
            float x1i = ((unsigned)(x0 + 1) < 64u) ? 1.f : 0.f;
            float w00 = (1.f - wy) * (1.f - wx) * m * y0i * x0i;
            float w01 = (1.f - wy) * wx         * m * y0i * x1i;
            float w10 = wy         * (1.f - wx) * m * y1i * x0i;
            float w11 = wy         * wx         * m * y1i * x1i;
            int cy0 = min(max(y0, 0), 63),     cy1 = min(max(y0 + 1, 0), 63);
            int cx0 = min(max(x0, 0), 63),     cx1 = min(max(x0 + 1, 0), 63);
            // window-relative rows; far if outside staged window [row-2,row+2]
            int s0 = cy0 - (row - 2); int s1 = cy1 - (row - 2);
            unsigned h00, h01, h10, h11;
            if (((unsigned)s0 > 4u) || ((unsigned)s1 > 4u)) {
                // far: store global pix (12b) + flag bit15 on every halfword
                h00 = 0x8000u | (unsigned)(cy0 * 64 + cx0);
                h01 = 0x8000u | (unsigned)(cy0 * 64 + cx1);
                h10 = 0x8000u | (unsigned)(cy1 * 64 + cx0);
                h11 = 0x8000u | (unsigned)(cy1 * 64 + cx1);
            } else {
                // pre-swizzled half-window byte addr (<= 20528, bit15 clear);
                // decode is h ^ q16 (base bits 4-5 are clear -> XOR == ADD)
                h00 = (unsigned)(((s0 * 64 + cx0) << 6) ^ ((cx0 & 7) << 4));
                h01 = (unsigned)(((s0 * 64 + cx1) << 6) ^ ((cx1 & 7) << 4));
                h10 = (unsigned)(((s1 * 64 + cx0) << 6) ^ ((cx0 & 7) << 4));
                h11 = (unsigned)(((s1 * 64 + cx1) << 6) ^ ((cx1 & 7) << 4));
            }
            sA[k * 64 + px] = make_uint2(h00 | (h01 << 16), h10 | (h11 << 16));
            sWp[k * 64 + px] = (f16x4){(_Float16)w00, (_Float16)w01, (_Float16)w10, (_Float16)w11};
        }
        __syncthreads();

        // ---- per-half pipelined LDS gather + B-frag register pipeline ----
        auto loadB_mn = [&](int S, int ot) -> f16x8 {
            int kb = (br * 72 + S * 4 + q) * 64;
            return *(const f16x8*)(wBp + (size_t)(kb + ot * 16 + n) * 8);
        };

        // Packed-f16 blend: per corner-dword one v_pk_fma_f16; af is
        // already packed f16 (no unpack, no repack).
#define PROC(Ca, Cb, Cc, Cd, WV, Wa, Wb, Wc, Wd)                               \
        {                                                                      \
            f16x2 pw0 = (f16x2){WV[0], WV[0]};                                 \
            f16x2 pw1 = (f16x2){WV[1], WV[1]};                                 \
            f16x2 pw2 = (f16x2){WV[2], WV[2]};                                 \
            f16x2 pw3 = (f16x2){WV[3], WV[3]};                                 \
            f16x2 a0 = bch(Ca.x) * pw0 + bch(Cb.x) * pw1                       \
                     + bch(Cc.x) * pw2 + bch(Cd.x) * pw3;                      \
            f16x2 a1 = bch(Ca.y) * pw0 + bch(Cb.y) * pw1                       \
                     + bch(Cc.y) * pw2 + bch(Cd.y) * pw3;                      \
            f16x2 a2 = bch(Ca.z) * pw0 + bch(Cb.z) * pw1                       \
                     + bch(Cc.z) * pw2 + bch(Cd.z) * pw3;                      \
            f16x2 a3 = bch(Ca.w) * pw0 + bch(Cb.w) * pw1                       \
                     + bch(Cc.w) * pw2 + bch(Cd.w) * pw3;                      \
            f16x8 af = (f16x8){a0[0], a0[1], a1[0], a1[1],                     \
                               a2[0], a2[1], a3[0], a3[1]};                    \
            __builtin_amdgcn_s_setprio(1);                                     \
            acc[0] = __builtin_amdgcn_mfma_f32_16x16x32_f16(af, Wa, acc[0], 0, 0, 0); \
            acc[1] = __builtin_amdgcn_mfma_f32_16x16x32_f16(af, Wb, acc[1], 0, 0, 0); \
            acc[2] = __builtin_amdgcn_mfma_f32_16x16x32_f16(af, Wc, acc[2], 0, 0, 0); \
            acc[3] = __builtin_amdgcn_mfma_f32_16x16x32_f16(af, Wd, acc[3], 0, 0, 0); \
            __builtin_amdgcn_s_setprio(0);                                     \
        }

        auto gather_pass = [&](int half) {
            const unsigned short* cbaseh = inT + q * 8 + half * 32;
            uint4 Ca0, Cb0, Cc0, Cd0, Ca1, Cb1, Cc1, Cd1;
            f16x4 wv0, wv1;
            f16x8 Ba0, Bb0, Bc0, Bd0, Ba1, Bb1, Bc1, Bd1;
            // load tap kt into the given register set (unconditional)
            auto loadTap = [&](int kt, uint4& Ca, uint4& Cb, uint4& Cc, uint4& Cd,
                               f16x4& wv, f16x8& Ba, f16x8& Bb, f16x8& Bc, f16x8& Bd) {
                uint2 aa = sA[kt * 64 + pxl];
                wv = sWp[kt * 64 + pxl];
                // pre-swizzled decode: and + XOR per corner (base bits 4-5
                // clear, q16 bits 4-5 only -> XOR == the original +q16)
                unsigned a00 = (aa.x & 0x7FFFu) ^ q16;
                unsigned a01 = ((aa.x >> 16) & 0x7FFFu) ^ q16;
                unsigned a10 = (aa.y & 0x7FFFu) ^ q16;
                unsigned a11 = ((aa.y >> 16) & 0x7FFFu) ^ q16;
                Ca = *(const uint4*)(arena + a00);
                Cb = *(const uint4*)(arena + a01);
                Cc = *(const uint4*)(arena + a10);
                Cd = *(const uint4*)(arena + a11);
                if (aa.x & 0x8000u) {  // rare: window miss -> global path
                    unsigned p00 = aa.x & 0xFFFu, p01 = (aa.x >> 16) & 0xFFFu;
                    unsigned p10 = aa.y & 0xFFFu, p11 = (aa.y >> 16) & 0xFFFu;
                    Ca = *(const uint4*)(cbaseh + (p00 << 6));
                    Cb = *(const uint4*)(cbaseh + (p01 << 6));
                    Cc = *(const uint4*)(cbaseh + (p10 << 6));
                    Cd = *(const uint4*)(cbaseh + (p11 << 6));
                }
                Ba = loadB_mn(kt * 2 + half, 0);
                Bb = loadB_mn(kt * 2 + half, 1);
                Bc = loadB_mn(kt * 2 + half, 2);
                Bd = loadB_mn(kt * 2 + half, 3);
            };
            loadTap(0, Ca0, Cb0, Cc0, Cd0, wv0, Ba0, Bb0, Bc0, Bd0);
#pragma unroll 1
            for (int kt = 0; kt < 4; ++kt) {
                loadTap(2 * kt + 1, Ca1, Cb1, Cc1, Cd1, wv1, Ba1, Bb1, Bc1, Bd1);
                PROC(Ca0, Cb0, Cc0, Cd0, wv0, Ba0, Bb0, Bc0, Bd0)
                loadTap(2 * kt + 2, Ca0, Cb0, Cc0, Cd0, wv0, Ba0, Bb0, Bc0, Bd0);
                PROC(Ca1, Cb1, Cc1, Cd1, wv1, Ba1, Bb1, Bc1, Bd1)
            }
            PROC(Ca0, Cb0, Cc0, Cd0, wv0, Ba0, Bb0, Bc0, Bd0)   // tap 8
        };

        gather_pass(1);            // window currently holds half-1
        __syncthreads();           // all waves done reading half-1 window
        stage_half(0);
        __syncthreads();
        gather_pass(0);
#undef PROC
    }

    // ---- epilogue: descramble via LDS -> natural [gate][b][o][row][px] ----
    __syncthreads();               // arena fully dead (all gathers done)
    float* sG = (float*)arena;     // [64 o][66] stride-66 f32, 16896 B
#pragma unroll
    for (int ot = 0; ot < 4; ++ot) {
        int o = ot * 16 + n;
#pragma unroll
        for (int r = 0; r < 4; ++r)
            sG[o * 66 + (w * 16 + q * 4 + r)] = acc[ot][r];
    }
    __syncthreads();
    float* gp = p.ws + WS_GATES + (size_t)gate * PLANE
              + (((size_t)b * 64) << 12) + row * 64;
#pragma unroll
    for (int ii = 0; ii < 16; ++ii) {
        int i = t + ii * 256;
        int o = i >> 6; int px = i & 63;
        gp[((size_t)o << 12) + px] = sG[o * 66 + px];
    }
}

// ---------------------------------------------------------------------------
// K3: pointwise ConvLSTM combine — fully linear (gates natural layout
//   matches c/out CHW). grid: 8192 blocks of 256.
// ---------------------------------------------------------------------------
__global__ __launch_bounds__(256) void k3_lstm(Params p) {
    size_t T = (size_t)blockIdx.x * 256 + threadIdx.x;   // linear over [b][o][row][px]
    const float* gp = p.ws + WS_GATES;
    float gi = gp[T];
    float gf = gp[T + 1 * (size_t)PLANE];
    float gc = gp[T + 2 * (size_t)PLANE];
    float go = gp[T + 3 * (size_t)PLANE];
    int o = ((int)(T >> 12)) & 63;
    float cold = p.c[T];
    float ig = sigf(gi + cold * p.wci[o] + p.bi[o]);
    float fg = sigf(gf + cold * p.wcf[o] + p.bf[o]);
    float cn = fg * cold + ig * tanhfast(gc + p.bc[o]);
    float og = sigf(go + cn * p.wco[o] + p.bo[o]);
    p.out[T] = og * tanhfast(cn);
    p.out[T + (size_t)PLANE] = cn;
}

// ---------------------------------------------------------------------------
extern "C" void kernel_launch(void* const* d_in, const int* in_sizes, int n_in,
                              void* d_out, int out_size, void* d_ws, size_t ws_size,
                              hipStream_t stream) {
    (void)in_sizes; (void)n_in; (void)out_size; (void)ws_size;
    Params P;
    P.x = (const float*)d_in[0];
    P.h = (const float*)d_in[1];
    P.c = (const float*)d_in[2];
    for (int i = 0; i < 8; ++i) {
        P.w[i]  = (const float*)d_in[3 + 3 * i];
        P.ow[i] = (const float*)d_in[4 + 3 * i];
        P.ob[i] = (const float*)d_in[5 + 3 * i];
    }
    P.bi  = (const float*)d_in[27];
    P.bf  = (const float*)d_in[28];
    P.bc  = (const float*)d_in[29];
    P.bo  = (const float*)d_in[30];
    P.wci = (const float*)d_in[31];
    P.wcf = (const float*)d_in[32];
    P.wco = (const float*)d_in[33];
    P.out = (float*)d_out;
    P.ws  = (float*)d_ws;

    k0_prep   <<<dim3(2753), dim3(256), 0, stream>>>(P);
    k2_fused  <<<dim3(2048), dim3(256), 0, stream>>>(P);
    k3_lstm   <<<dim3(8192), dim3(256), 0, stream>>>(P);
}